// Round 2
// baseline (374.539 us; speedup 1.0000x reference)
//
#include <hip/hip_runtime.h>
#include <cstdint>
#include <cstddef>

#define DEV __device__ __forceinline__

typedef __attribute__((ext_vector_type(8))) __bf16 bf16x8;
typedef __attribute__((ext_vector_type(4))) float f32x4;
typedef __attribute__((ext_vector_type(8))) unsigned short u16x8;

typedef const __attribute__((address_space(1))) void gld_gv;
typedef __attribute__((address_space(3))) void gld_sv;

static constexpr int SEQ = 2048, BAT = 2, DM = 1024, DFF = 4096;
static constexpr int MT = BAT * SEQ;  // 4096 rows total

DEV unsigned short f2bf_bits(float f) {
    uint32_t u = __builtin_bit_cast(uint32_t, f);
    return (unsigned short)((u + 0x7FFFu + ((u >> 16) & 1u)) >> 16);
}

DEV void gload16(const void* g, void* s) {
    __builtin_amdgcn_global_load_lds((gld_gv*)g, (gld_sv*)s, 16, 0, 0);
}

// ---------------- weight transpose + fp32->bf16 convert ----------------
// W [K][N] f32  ->  WT [N][K] bf16.  grid (K/64, N/64), block 256.
__global__ __launch_bounds__(256) void wtrans_kernel(const float* __restrict__ W,
        unsigned short* __restrict__ WT, int K, int N)
{
    __shared__ float tile[64][65];
    const int k0 = blockIdx.x * 64, n0 = blockIdx.y * 64;
    const int t = threadIdx.x, r = t >> 6, c = t & 63;
    #pragma unroll
    for (int p = 0; p < 16; ++p)
        tile[p * 4 + r][c] = W[(size_t)(k0 + p * 4 + r) * N + n0 + c];
    __syncthreads();
    #pragma unroll
    for (int p = 0; p < 16; ++p)
        WT[(size_t)(n0 + p * 4 + r) * K + k0 + c] = f2bf_bits(tile[c][p * 4 + r]);
}

// ---------------- LayerNorm (f32 in -> bf16 out) ----------------
__global__ __launch_bounds__(256) void ln_kernel(const float* __restrict__ x,
        const float* __restrict__ gw, const float* __restrict__ bw,
        unsigned short* __restrict__ y)
{
    const int row = blockIdx.x, t = threadIdx.x;
    const float* xr = x + (size_t)row * DM;
    float4 v = *(const float4*)(xr + t * 4);
    float s = v.x + v.y + v.z + v.w;
    float q = v.x * v.x + v.y * v.y + v.z * v.z + v.w * v.w;
    #pragma unroll
    for (int m = 1; m < 64; m <<= 1) { s += __shfl_xor(s, m); q += __shfl_xor(q, m); }
    __shared__ float red[8];
    const int w = t >> 6;
    if ((t & 63) == 0) { red[w] = s; red[4 + w] = q; }
    __syncthreads();
    s = red[0] + red[1] + red[2] + red[3];
    q = red[4] + red[5] + red[6] + red[7];
    const float mu = s * (1.0f / DM);
    const float rstd = rsqrtf(q * (1.0f / DM) - mu * mu + 1e-5f);
    float4 g4 = *(const float4*)(gw + t * 4);
    float4 b4 = *(const float4*)(bw + t * 4);
    short4 o;
    o.x = (short)f2bf_bits((v.x - mu) * rstd * g4.x + b4.x);
    o.y = (short)f2bf_bits((v.y - mu) * rstd * g4.y + b4.y);
    o.z = (short)f2bf_bits((v.z - mu) * rstd * g4.z + b4.z);
    o.w = (short)f2bf_bits((v.w - mu) * rstd * g4.w + b4.w);
    *(short4*)(y + (size_t)row * DM + t * 4) = o;
}

// ---------------- GEMM: C[M][N] = A[M][K] @ B, BT[N][K] given (both bf16) ---
// EPI 0: bf16 out, *scale   1: f32 out + res   2: +bias, GELU, bf16   3: +bias +res, f32
template<int EPI>
__global__ __launch_bounds__(256, 2) void gemm_kernel(
    const unsigned short* __restrict__ A, const unsigned short* __restrict__ BT,
    void* __restrict__ Cp, const float* __restrict__ bias,
    const float* __restrict__ res, int Nsz, int Ksz, float scale)
{
    __shared__ alignas(16) unsigned short ldsA[128 * 64];
    __shared__ alignas(16) unsigned short ldsB[128 * 64];
    const int t = threadIdx.x, l = t & 63, w = t >> 6;
    const int wm = w >> 1, wn = w & 1, lr = l & 15, lg = l >> 4;
    const int bm = blockIdx.x, bn = blockIdx.y;

    f32x4 acc[4][4] = {};

    const int srow = t >> 3, scol = (t & 7) * 8;  // elements
    const unsigned short* Ab = A + (size_t)(bm * 128 + srow) * Ksz + scol;
    const unsigned short* Bb = BT + (size_t)(bn * 128 + srow) * Ksz + scol;
    char* la = (char*)ldsA;
    char* lb = (char*)ldsB;

    for (int k0 = 0; k0 < Ksz; k0 += 64) {
        __syncthreads();
        #pragma unroll
        for (int p = 0; p < 4; ++p) {
            gload16(Ab + (size_t)(p * 32) * Ksz + k0, la + p * 4096 + t * 16);
            gload16(Bb + (size_t)(p * 32) * Ksz + k0, lb + p * 4096 + t * 16);
        }
        __syncthreads();
        #pragma unroll
        for (int ks = 0; ks < 2; ++ks) {
            bf16x8 af[4], bfr[4];
            #pragma unroll
            for (int i = 0; i < 4; ++i) {
                af[i]  = *(const bf16x8*)(la + (wm * 64 + i * 16 + lr) * 128 + ks * 64 + lg * 16);
                bfr[i] = *(const bf16x8*)(lb + (wn * 64 + i * 16 + lr) * 128 + ks * 64 + lg * 16);
            }
            #pragma unroll
            for (int mb = 0; mb < 4; ++mb)
                #pragma unroll
                for (int nb = 0; nb < 4; ++nb)
                    acc[mb][nb] = __builtin_amdgcn_mfma_f32_16x16x32_bf16(
                        af[mb], bfr[nb], acc[mb][nb], 0, 0, 0);
        }
    }

    const int rb = bm * 128 + wm * 64, cb = bn * 128 + wn * 64;
    #pragma unroll
    for (int mb = 0; mb < 4; ++mb)
        #pragma unroll
        for (int nb = 0; nb < 4; ++nb)
            #pragma unroll
            for (int r = 0; r < 4; ++r) {
                const int row = rb + mb * 16 + lg * 4 + r;
                const int col = cb + nb * 16 + lr;
                const size_t idx = (size_t)row * Nsz + col;
                float v = acc[mb][nb][r];
                if (EPI == 0) {
                    ((unsigned short*)Cp)[idx] = f2bf_bits(v * scale);
                } else if (EPI == 1) {
                    ((float*)Cp)[idx] = v + res[idx];
                } else if (EPI == 2) {
                    float xx = v + bias[col];
                    ((unsigned short*)Cp)[idx] =
                        f2bf_bits(0.5f * xx * (1.0f + erff(xx * 0.70710678118654752f)));
                } else {
                    ((float*)Cp)[idx] = v + bias[col] + res[idx];
                }
            }
}

// ---------------- causal flash attention ----------------
// Q,K,V,O: [MT][DM] bf16, head h at cols h*64..h*64+63. Q pre-scaled by 1/8.
// grid (B*H=32, S/64=32), block 256 (4 waves, 16 q-rows each).
// All MFMA operand placements here are pairwise self-consistent:
//   QK^T: K-frag and Q-frag both use contiguous dk slots.
//   PV:   P-slot map is forced by QK^T's C-layout -> f(lg,j)=16*(j>>2)+lg*4+(j&3);
//         V fragments are read from a transposed LDS tile VT[n][k] at exactly
//         that same map, via plain ds_read_b64 (no tr-read assumption).
static constexpr int VSTR = 72;  // VT row stride in elements (144B, 8B-aligned)

__global__ __launch_bounds__(256, 2) void attn_kernel(
    const unsigned short* __restrict__ Qg, const unsigned short* __restrict__ Kg,
    const unsigned short* __restrict__ Vg, unsigned short* __restrict__ Og)
{
    __shared__ alignas(16) unsigned short ldsK[64 * 64];
    __shared__ alignas(16) unsigned short ldsVT[64 * VSTR];
    const int t = threadIdx.x, l = t & 63, w = t >> 6;
    const int lr = l & 15, lg = l >> 4;
    const int bh = blockIdx.x, qt = blockIdx.y;
    const int b = bh >> 4, h = bh & 15;
    const size_t hbase = (size_t)b * SEQ * DM + (size_t)h * 64;

    const int ql = w * 16 + lr;  // q local in 64-row tile
    bf16x8 qf[2];
    #pragma unroll
    for (int ks = 0; ks < 2; ++ks)
        qf[ks] = *(const bf16x8*)(Qg + hbase + (size_t)(qt * 64 + ql) * DM + ks * 32 + lg * 8);

    float m_run = -1e30f, l_run = 0.0f;
    f32x4 oacc[4] = {};

    const int krow = t >> 3, kcol = (t & 7) * 8;

    for (int kt = 0; kt <= qt; ++kt) {
        const unsigned short* Kt = Kg + hbase + (size_t)(kt * 64) * DM;
        const unsigned short* Vt = Vg + hbase + (size_t)(kt * 64) * DM;
        __syncthreads();
        #pragma unroll
        for (int p = 0; p < 2; ++p) {
            gload16(Kt + (size_t)(p * 32 + krow) * DM + kcol, (char*)ldsK + p * 4096 + t * 16);
        }
        // stage V transposed: VT[n][k ^ ((n&7)*4)] = V[k][n]  (swizzle vs bank conflicts)
        #pragma unroll
        for (int p = 0; p < 2; ++p) {
            const int k = p * 32 + krow;        // 0..63
            const int n0 = kcol;                // 0,8,...,56
            u16x8 gl = *(const u16x8*)(Vt + (size_t)k * DM + n0);
            #pragma unroll
            for (int i = 0; i < 8; ++i)
                ldsVT[(n0 + i) * VSTR + (k ^ (((n0 + i) & 7) * 4))] = gl[i];
        }
        __syncthreads();

        // S^T = K · Q^T : lane holds q = lr, key = mb*16 + lg*4 + reg
        f32x4 st[4] = {};
        #pragma unroll
        for (int ks = 0; ks < 2; ++ks)
            #pragma unroll
            for (int mb = 0; mb < 4; ++mb) {
                bf16x8 kf = *(const bf16x8*)((char*)ldsK + (mb * 16 + lr) * 128 + ks * 64 + lg * 16);
                st[mb] = __builtin_amdgcn_mfma_f32_16x16x32_bf16(kf, qf[ks], st[mb], 0, 0, 0);
            }

        if (kt == qt) {
            #pragma unroll
            for (int mb = 0; mb < 4; ++mb)
                #pragma unroll
                for (int r = 0; r < 4; ++r)
                    if (mb * 16 + lg * 4 + r > ql) st[mb][r] = -1e30f;
        }

        float mt = -1e30f;
        #pragma unroll
        for (int mb = 0; mb < 4; ++mb)
            mt = fmaxf(mt, fmaxf(fmaxf(st[mb][0], st[mb][1]), fmaxf(st[mb][2], st[mb][3])));
        mt = fmaxf(mt, __shfl_xor(mt, 16));
        mt = fmaxf(mt, __shfl_xor(mt, 32));
        const float m_new = fmaxf(m_run, mt);
        float pr[4][4];
        float rs = 0.0f;
        #pragma unroll
        for (int mb = 0; mb < 4; ++mb)
            #pragma unroll
            for (int r = 0; r < 4; ++r) {
                pr[mb][r] = exp2f((st[mb][r] - m_new) * 1.44269504089f);
                rs += pr[mb][r];
            }
        rs += __shfl_xor(rs, 16);
        rs += __shfl_xor(rs, 32);
        const float alpha = exp2f((m_run - m_new) * 1.44269504089f);
        l_run = l_run * alpha + rs;
        m_run = m_new;
        #pragma unroll
        for (int j = 0; j < 4; ++j) {
            const float aj = __shfl(alpha, lg * 4 + j);
            #pragma unroll
            for (int nb = 0; nb < 4; ++nb) oacc[nb][j] *= aj;
        }
        // P -> A-frags in-register. Slot map f(lg,j) = 16*(j>>2) + lg*4 + (j&3)
        // within each 32-key window ks (keys = 32*ks + f).
        union { bf16x8 v; unsigned short u[8]; } pa[2];
        #pragma unroll
        for (int ks = 0; ks < 2; ++ks)
            #pragma unroll
            for (int j = 0; j < 4; ++j) {
                pa[ks].u[j]     = f2bf_bits(pr[2 * ks][j]);      // k = 32ks + lg*4 + j
                pa[ks].u[j + 4] = f2bf_bits(pr[2 * ks + 1][j]);  // k = 32ks + 16 + lg*4 + j
            }
        // V B-frags from VT at the SAME slot map: slot j holds V[32ks + f(lg,j)][n=16nb+lr]
        #pragma unroll
        for (int ks = 0; ks < 2; ++ks)
            #pragma unroll
            for (int nb = 0; nb < 4; ++nb) {
                const int n = nb * 16 + lr;
                const int swz = (n & 7) * 4;
                union { bf16x8 v; uint64_t d[2]; } vb;
                vb.d[0] = *(const uint64_t*)&ldsVT[n * VSTR + ((ks * 32 + lg * 4) ^ swz)];
                vb.d[1] = *(const uint64_t*)&ldsVT[n * VSTR + ((ks * 32 + 16 + lg * 4) ^ swz)];
                oacc[nb] = __builtin_amdgcn_mfma_f32_16x16x32_bf16(pa[ks].v, vb.v, oacc[nb], 0, 0, 0);
            }
    }

    unsigned short* Ob = Og + hbase + (size_t)(qt * 64) * DM;
    #pragma unroll
    for (int j = 0; j < 4; ++j) {
        const float inv = 1.0f / __shfl(l_run, lg * 4 + j);
        const int row = w * 16 + lg * 4 + j;
        #pragma unroll
        for (int nb = 0; nb < 4; ++nb)
            Ob[(size_t)row * DM + nb * 16 + lr] = f2bf_bits(oacc[nb][j] * inv);
    }
}

// ---------------- launcher ----------------
extern "C" void kernel_launch(void* const* d_in, const int* in_sizes, int n_in,
                              void* d_out, int out_size, void* d_ws, size_t ws_size,
                              hipStream_t stream) {
    (void)in_sizes; (void)n_in; (void)out_size; (void)ws_size;
    const float* x    = (const float*)d_in[0];
    const float* Wq   = (const float*)d_in[1];
    const float* Wk   = (const float*)d_in[2];
    const float* Wv   = (const float*)d_in[3];
    const float* Wo   = (const float*)d_in[4];
    const float* ln1g = (const float*)d_in[5];
    const float* ln1b = (const float*)d_in[6];
    const float* ln2g = (const float*)d_in[7];
    const float* ln2b = (const float*)d_in[8];
    const float* W1   = (const float*)d_in[9];
    const float* b1   = (const float*)d_in[10];
    const float* W2   = (const float*)d_in[11];
    const float* b2   = (const float*)d_in[12];
    float* out = (float*)d_out;

    char* ws = (char*)d_ws;
    const size_t MB = 1ull << 20;
    unsigned short* xn1   = (unsigned short*)(ws + 0 * MB);   // 8 MB
    unsigned short* Qb    = (unsigned short*)(ws + 8 * MB);   // 8 MB
    unsigned short* Kb    = (unsigned short*)(ws + 16 * MB);  // 8 MB
    unsigned short* Vb    = (unsigned short*)(ws + 24 * MB);  // 8 MB
    unsigned short* ffa   = (unsigned short*)(ws + 0 * MB);   // 32 MB (aliases xn1/Q/K/V after attn)
    unsigned short* attno = (unsigned short*)(ws + 32 * MB);  // 8 MB
    float*          x2    = (float*)(ws + 40 * MB);           // 16 MB
    unsigned short* h2    = (unsigned short*)(ws + 56 * MB);  // 8 MB
    unsigned short* WqT   = (unsigned short*)(ws + 64 * MB);  // 2 MB each
    unsigned short* WkT   = (unsigned short*)(ws + 66 * MB);
    unsigned short* WvT   = (unsigned short*)(ws + 68 * MB);
    unsigned short* WoT   = (unsigned short*)(ws + 70 * MB);
    unsigned short* W1T   = (unsigned short*)(ws + 72 * MB);  // 8 MB
    unsigned short* W2T   = (unsigned short*)(ws + 80 * MB);  // 8 MB  (total 88 MB)

    dim3 blk(256);
    wtrans_kernel<<<dim3(16, 16), blk, 0, stream>>>(Wq, WqT, DM, DM);
    wtrans_kernel<<<dim3(16, 16), blk, 0, stream>>>(Wk, WkT, DM, DM);
    wtrans_kernel<<<dim3(16, 16), blk, 0, stream>>>(Wv, WvT, DM, DM);
    wtrans_kernel<<<dim3(16, 16), blk, 0, stream>>>(Wo, WoT, DM, DM);
    wtrans_kernel<<<dim3(16, 64), blk, 0, stream>>>(W1, W1T, DM, DFF);
    wtrans_kernel<<<dim3(64, 16), blk, 0, stream>>>(W2, W2T, DFF, DM);

    ln_kernel<<<dim3(MT), blk, 0, stream>>>(x, ln1g, ln1b, xn1);

    gemm_kernel<0><<<dim3(32, 8), blk, 0, stream>>>(xn1, WqT, Qb, nullptr, nullptr, DM, DM, 0.125f);
    gemm_kernel<0><<<dim3(32, 8), blk, 0, stream>>>(xn1, WkT, Kb, nullptr, nullptr, DM, DM, 1.0f);
    gemm_kernel<0><<<dim3(32, 8), blk, 0, stream>>>(xn1, WvT, Vb, nullptr, nullptr, DM, DM, 1.0f);

    attn_kernel<<<dim3(32, 32), blk, 0, stream>>>(Qb, Kb, Vb, attno);

    gemm_kernel<1><<<dim3(32, 8), blk, 0, stream>>>(attno, WoT, x2, nullptr, x, DM, DM, 1.0f);

    ln_kernel<<<dim3(MT), blk, 0, stream>>>(x2, ln2g, ln2b, h2);

    gemm_kernel<2><<<dim3(32, 32), blk, 0, stream>>>(h2, W1T, ffa, b1, nullptr, DFF, DM, 1.0f);
    gemm_kernel<3><<<dim3(32, 8), blk, 0, stream>>>(ffa, W2T, out, b2, x2, DM, DFF, 1.0f);
}

// Round 3
// 347.036 us; speedup vs baseline: 1.0793x; 1.0793x over previous
//
#include <hip/hip_runtime.h>
#include <cstdint>
#include <cstddef>

#define DEV __device__ __forceinline__

typedef __attribute__((ext_vector_type(8))) __bf16 bf16x8;
typedef __attribute__((ext_vector_type(4))) float f32x4;
typedef __attribute__((ext_vector_type(8))) unsigned short u16x8;

typedef const __attribute__((address_space(1))) void gld_gv;
typedef __attribute__((address_space(3))) void gld_sv;

static constexpr int SEQ = 2048, BAT = 2, DM = 1024, DFF = 4096;
static constexpr int MT = BAT * SEQ;  // 4096 rows total

DEV unsigned short f2bf_bits(float f) {
    uint32_t u = __builtin_bit_cast(uint32_t, f);
    return (unsigned short)((u + 0x7FFFu + ((u >> 16) & 1u)) >> 16);
}

DEV void gload16(const void* g, void* s) {
    __builtin_amdgcn_global_load_lds((gld_gv*)g, (gld_sv*)s, 16, 0, 0);
}

// ---------------- weight transpose + fp32->bf16 convert (+scale) -----------
// W [K][N] f32  ->  WT [N][K] bf16 * scale.  grid (K/64, N/64), block 256.
__global__ __launch_bounds__(256) void wtrans_kernel(const float* __restrict__ W,
        unsigned short* __restrict__ WT, int K, int N, float scale)
{
    __shared__ float tile[64][65];
    const int k0 = blockIdx.x * 64, n0 = blockIdx.y * 64;
    const int t = threadIdx.x, r = t >> 6, c = t & 63;
    #pragma unroll
    for (int p = 0; p < 16; ++p)
        tile[p * 4 + r][c] = W[(size_t)(k0 + p * 4 + r) * N + n0 + c];
    __syncthreads();
    #pragma unroll
    for (int p = 0; p < 16; ++p)
        WT[(size_t)(n0 + p * 4 + r) * K + k0 + c] = f2bf_bits(tile[c][p * 4 + r] * scale);
}

// ---------------- LayerNorm (f32 in -> bf16 out) ----------------
__global__ __launch_bounds__(256) void ln_kernel(const float* __restrict__ x,
        const float* __restrict__ gw, const float* __restrict__ bw,
        unsigned short* __restrict__ y)
{
    const int row = blockIdx.x, t = threadIdx.x;
    const float* xr = x + (size_t)row * DM;
    float4 v = *(const float4*)(xr + t * 4);
    float s = v.x + v.y + v.z + v.w;
    float q = v.x * v.x + v.y * v.y + v.z * v.z + v.w * v.w;
    #pragma unroll
    for (int m = 1; m < 64; m <<= 1) { s += __shfl_xor(s, m); q += __shfl_xor(q, m); }
    __shared__ float red[8];
    const int w = t >> 6;
    if ((t & 63) == 0) { red[w] = s; red[4 + w] = q; }
    __syncthreads();
    s = red[0] + red[1] + red[2] + red[3];
    q = red[4] + red[5] + red[6] + red[7];
    const float mu = s * (1.0f / DM);
    const float rstd = rsqrtf(q * (1.0f / DM) - mu * mu + 1e-5f);
    float4 g4 = *(const float4*)(gw + t * 4);
    float4 b4 = *(const float4*)(bw + t * 4);
    short4 o;
    o.x = (short)f2bf_bits((v.x - mu) * rstd * g4.x + b4.x);
    o.y = (short)f2bf_bits((v.y - mu) * rstd * g4.y + b4.y);
    o.z = (short)f2bf_bits((v.z - mu) * rstd * g4.z + b4.z);
    o.w = (short)f2bf_bits((v.w - mu) * rstd * g4.w + b4.w);
    *(short4*)(y + (size_t)row * DM + t * 4) = o;
}

// ---------------- GEMM: C[M][N] = A[M][K] @ B, BT[N][K] given (both bf16) ---
// EPI 0: bf16 out, *scale      1: f32 out + res     2: +bias, GELU, bf16
// EPI 3: +bias +res, f32       4: bf16 out TRANSPOSED per-head (V^T producer)
template<int EPI>
__global__ __launch_bounds__(256, 2) void gemm_kernel(
    const unsigned short* __restrict__ A, const unsigned short* __restrict__ BT,
    void* __restrict__ Cp, const float* __restrict__ bias,
    const float* __restrict__ res, int Nsz, int Ksz, float scale)
{
    __shared__ alignas(16) unsigned short ldsA[128 * 64];
    __shared__ alignas(16) unsigned short ldsB[128 * 64];
    const int t = threadIdx.x, l = t & 63, w = t >> 6;
    const int wm = w >> 1, wn = w & 1, lr = l & 15, lg = l >> 4;
    const int bm = blockIdx.x, bn = blockIdx.y;

    f32x4 acc[4][4] = {};

    const int srow = t >> 3, scol = (t & 7) * 8;  // elements
    const unsigned short* Ab = A + (size_t)(bm * 128 + srow) * Ksz + scol;
    const unsigned short* Bb = BT + (size_t)(bn * 128 + srow) * Ksz + scol;
    char* la = (char*)ldsA;
    char* lb = (char*)ldsB;

    for (int k0 = 0; k0 < Ksz; k0 += 64) {
        __syncthreads();
        #pragma unroll
        for (int p = 0; p < 4; ++p) {
            gload16(Ab + (size_t)(p * 32) * Ksz + k0, la + p * 4096 + t * 16);
            gload16(Bb + (size_t)(p * 32) * Ksz + k0, lb + p * 4096 + t * 16);
        }
        __syncthreads();
        #pragma unroll
        for (int ks = 0; ks < 2; ++ks) {
            bf16x8 af[4], bfr[4];
            #pragma unroll
            for (int i = 0; i < 4; ++i) {
                af[i]  = *(const bf16x8*)(la + (wm * 64 + i * 16 + lr) * 128 + ks * 64 + lg * 16);
                bfr[i] = *(const bf16x8*)(lb + (wn * 64 + i * 16 + lr) * 128 + ks * 64 + lg * 16);
            }
            #pragma unroll
            for (int mb = 0; mb < 4; ++mb)
                #pragma unroll
                for (int nb = 0; nb < 4; ++nb) {
                    if (EPI == 4)  // swapped operands -> transposed output tile
                        acc[mb][nb] = __builtin_amdgcn_mfma_f32_16x16x32_bf16(
                            bfr[nb], af[mb], acc[mb][nb], 0, 0, 0);
                    else
                        acc[mb][nb] = __builtin_amdgcn_mfma_f32_16x16x32_bf16(
                            af[mb], bfr[nb], acc[mb][nb], 0, 0, 0);
                }
        }
    }

    const int rb = bm * 128 + wm * 64, cb = bn * 128 + wn * 64;
    #pragma unroll
    for (int mb = 0; mb < 4; ++mb)
        #pragma unroll
        for (int nb = 0; nb < 4; ++nb)
            #pragma unroll
            for (int r = 0; r < 4; ++r) {
                float v = acc[mb][nb][r];
                if (EPI == 4) {
                    // D rows = B-tile (features), D cols = A rows (tokens)
                    const int xrow = rb + mb * 16 + lr;          // token row
                    const int feat = cb + nb * 16 + lg * 4 + r;  // output feature
                    const int bb = xrow >> 11, s = xrow & (SEQ - 1);
                    ((unsigned short*)Cp)[((size_t)bb * DM + feat) * SEQ + s] = f2bf_bits(v);
                    continue;
                }
                const int row = rb + mb * 16 + lg * 4 + r;
                const int col = cb + nb * 16 + lr;
                const size_t idx = (size_t)row * Nsz + col;
                if (EPI == 0) {
                    ((unsigned short*)Cp)[idx] = f2bf_bits(v * scale);
                } else if (EPI == 1) {
                    ((float*)Cp)[idx] = v + res[idx];
                } else if (EPI == 2) {
                    float xx = v + bias[col];
                    ((unsigned short*)Cp)[idx] =
                        f2bf_bits(0.5f * xx * (1.0f + erff(xx * 0.70710678118654752f)));
                } else {
                    ((float*)Cp)[idx] = v + bias[col] + res[idx];
                }
            }
}

// ---------------- causal flash attention ----------------
// QKg: [B][S][2048] bf16 (Q | K fused, Q pre-scaled 1/8), head h at cols h*64 / 1024+h*64.
// VTg: [B][DM][S] bf16 (V transposed per head: row = feature, col = token).
// Og:  [B][S][DM] bf16.
// grid (16 qtiles, 32 bh), block 512 (8 waves, 16 q-rows each; QBLK=128, KVB=64).
// K and VT tiles staged swizzled: lds 16B-chunk c of row r holds global chunk c^(r&7).
__global__ __launch_bounds__(512, 2) void attn_kernel(
    const unsigned short* __restrict__ QKg, const unsigned short* __restrict__ VTg,
    unsigned short* __restrict__ Og)
{
    __shared__ alignas(16) unsigned short ldsK[64 * 64];
    __shared__ alignas(16) unsigned short ldsVT[64 * 64];
    const int t = threadIdx.x, l = t & 63, w = t >> 6;
    const int lr = l & 15, lg = l >> 4;
    const int qt = (int)gridDim.x - 1 - blockIdx.x;  // longest blocks first
    const int bh = blockIdx.y;
    const int b = bh >> 4, h = bh & 15;
    const unsigned short* Qbase = QKg + (size_t)b * SEQ * 2048 + h * 64;
    const unsigned short* Kbase = Qbase + 1024;
    const unsigned short* Vbase = VTg + (size_t)b * DM * SEQ + (size_t)(h * 64) * SEQ;

    const int wq0 = qt * 128 + w * 16;   // wave's first q row
    const int qrow = wq0 + lr;           // this lane's q row
    bf16x8 qf[2];
    #pragma unroll
    for (int ks = 0; ks < 2; ++ks)
        qf[ks] = *(const bf16x8*)(Qbase + (size_t)qrow * 2048 + ks * 32 + lg * 8);

    float m_run = -1e30f, l_run = 0.0f;
    f32x4 oacc[4] = {};

    const int srow = t >> 3, scs = (t & 7) ^ (srow & 7);  // swizzled source chunk
    char* lk = (char*)ldsK;
    char* lv = (char*)ldsVT;

    const int nkt = 2 * qt + 2;
    for (int kt = 0; kt < nkt; ++kt) {
        __syncthreads();
        gload16(Kbase + (size_t)(kt * 64 + srow) * 2048 + scs * 8, lk + t * 16);
        gload16(Vbase + (size_t)srow * SEQ + kt * 64 + scs * 8, lv + t * 16);
        __syncthreads();

        // S^T = K · Q^T : lane holds q = lr, key = mb*16 + lg*4 + reg
        f32x4 st[4] = {};
        #pragma unroll
        for (int ks = 0; ks < 2; ++ks)
            #pragma unroll
            for (int mb = 0; mb < 4; ++mb) {
                bf16x8 kf = *(const bf16x8*)(lk + (mb * 16 + lr) * 128
                                             + (((ks * 4 + lg) ^ (lr & 7)) * 16));
                st[mb] = __builtin_amdgcn_mfma_f32_16x16x32_bf16(kf, qf[ks], st[mb], 0, 0, 0);
            }

        const int kt0 = kt * 64;
        if (kt0 + 63 > wq0) {  // wave-uniform: diagonal or beyond
            #pragma unroll
            for (int mb = 0; mb < 4; ++mb)
                #pragma unroll
                for (int r = 0; r < 4; ++r)
                    if (kt0 + mb * 16 + lg * 4 + r > qrow) st[mb][r] = -1e30f;
        }

        float mt = -1e30f;
        #pragma unroll
        for (int mb = 0; mb < 4; ++mb)
            mt = fmaxf(mt, fmaxf(fmaxf(st[mb][0], st[mb][1]), fmaxf(st[mb][2], st[mb][3])));
        mt = fmaxf(mt, __shfl_xor(mt, 16));
        mt = fmaxf(mt, __shfl_xor(mt, 32));
        const float m_new = fmaxf(m_run, mt);
        float pr[4][4];
        float rs = 0.0f;
        #pragma unroll
        for (int mb = 0; mb < 4; ++mb)
            #pragma unroll
            for (int r = 0; r < 4; ++r) {
                pr[mb][r] = exp2f((st[mb][r] - m_new) * 1.44269504089f);
                rs += pr[mb][r];
            }
        rs += __shfl_xor(rs, 16);
        rs += __shfl_xor(rs, 32);
        const float alpha = exp2f((m_run - m_new) * 1.44269504089f);
        l_run = l_run * alpha + rs;
        m_run = m_new;
        #pragma unroll
        for (int j = 0; j < 4; ++j) {
            const float aj = __shfl(alpha, lg * 4 + j);
            #pragma unroll
            for (int nb = 0; nb < 4; ++nb) oacc[nb][j] *= aj;
        }
        // P -> A-frags in-register. Slot map f(lg,j) = 16*(j>>2) + lg*4 + (j&3),
        // keys = 32*ks + f.
        union { bf16x8 v; unsigned short u[8]; } pa[2];
        #pragma unroll
        for (int ks = 0; ks < 2; ++ks)
            #pragma unroll
            for (int j = 0; j < 4; ++j) {
                pa[ks].u[j]     = f2bf_bits(pr[2 * ks][j]);
                pa[ks].u[j + 4] = f2bf_bits(pr[2 * ks + 1][j]);
            }
        // V B-frags from swizzled VT rows: slot j holds V[32ks+f(lg,j)][n=16nb+lr]
        #pragma unroll
        for (int ks = 0; ks < 2; ++ks)
            #pragma unroll
            for (int nb = 0; nb < 4; ++nb) {
                const int n = nb * 16 + lr;
                union { bf16x8 v; uint64_t d[2]; } vb;
                vb.d[0] = *(const uint64_t*)(lv + n * 128
                            + (((4 * ks + (lg >> 1)) ^ (n & 7)) * 16) + 8 * (lg & 1));
                vb.d[1] = *(const uint64_t*)(lv + n * 128
                            + (((4 * ks + 2 + (lg >> 1)) ^ (n & 7)) * 16) + 8 * (lg & 1));
                oacc[nb] = __builtin_amdgcn_mfma_f32_16x16x32_bf16(pa[ks].v, vb.v, oacc[nb], 0, 0, 0);
            }
    }

    unsigned short* Ob = Og + (size_t)b * SEQ * DM + h * 64;
    #pragma unroll
    for (int j = 0; j < 4; ++j) {
        const float inv = 1.0f / __shfl(l_run, lg * 4 + j);
        const int row = wq0 + lg * 4 + j;
        #pragma unroll
        for (int nb = 0; nb < 4; ++nb)
            Ob[(size_t)row * DM + nb * 16 + lr] = f2bf_bits(oacc[nb][j] * inv);
    }
}

// ---------------- launcher ----------------
extern "C" void kernel_launch(void* const* d_in, const int* in_sizes, int n_in,
                              void* d_out, int out_size, void* d_ws, size_t ws_size,
                              hipStream_t stream) {
    (void)in_sizes; (void)n_in; (void)out_size; (void)ws_size;
    const float* x    = (const float*)d_in[0];
    const float* Wq   = (const float*)d_in[1];
    const float* Wk   = (const float*)d_in[2];
    const float* Wv   = (const float*)d_in[3];
    const float* Wo   = (const float*)d_in[4];
    const float* ln1g = (const float*)d_in[5];
    const float* ln1b = (const float*)d_in[6];
    const float* ln2g = (const float*)d_in[7];
    const float* ln2b = (const float*)d_in[8];
    const float* W1   = (const float*)d_in[9];
    const float* b1   = (const float*)d_in[10];
    const float* W2   = (const float*)d_in[11];
    const float* b2   = (const float*)d_in[12];
    float* out = (float*)d_out;

    char* ws = (char*)d_ws;
    const size_t MB = 1ull << 20;
    unsigned short* xn1   = (unsigned short*)(ws + 0 * MB);   // 8 MB [4096][1024]
    unsigned short* QKb   = (unsigned short*)(ws + 8 * MB);   // 16 MB [2][2048][2048]
    unsigned short* VTg   = (unsigned short*)(ws + 24 * MB);  // 8 MB [2][1024][2048]
    unsigned short* ffa   = (unsigned short*)(ws + 0 * MB);   // 32 MB (aliases xn1/QKb/VTg)
    unsigned short* attno = (unsigned short*)(ws + 32 * MB);  // 8 MB
    float*          x2    = (float*)(ws + 40 * MB);           // 16 MB
    unsigned short* h2    = (unsigned short*)(ws + 56 * MB);  // 8 MB
    unsigned short* WqkT  = (unsigned short*)(ws + 64 * MB);  // 4 MB [2048][1024]
    unsigned short* WvT   = (unsigned short*)(ws + 68 * MB);  // 2 MB
    unsigned short* WoT   = (unsigned short*)(ws + 70 * MB);  // 2 MB
    unsigned short* W1T   = (unsigned short*)(ws + 72 * MB);  // 8 MB
    unsigned short* W2T   = (unsigned short*)(ws + 80 * MB);  // 8 MB  (total 88 MB)

    dim3 blk(256);
    wtrans_kernel<<<dim3(16, 16), blk, 0, stream>>>(Wq, WqkT, DM, DM, 0.125f);
    wtrans_kernel<<<dim3(16, 16), blk, 0, stream>>>(Wk, WqkT + DM * DM, DM, DM, 1.0f);
    wtrans_kernel<<<dim3(16, 16), blk, 0, stream>>>(Wv, WvT, DM, DM, 1.0f);
    wtrans_kernel<<<dim3(16, 16), blk, 0, stream>>>(Wo, WoT, DM, DM, 1.0f);
    wtrans_kernel<<<dim3(16, 64), blk, 0, stream>>>(W1, W1T, DM, DFF, 1.0f);
    wtrans_kernel<<<dim3(64, 16), blk, 0, stream>>>(W2, W2T, DFF, DM, 1.0f);

    ln_kernel<<<dim3(MT), blk, 0, stream>>>(x, ln1g, ln1b, xn1);

    // fused Q|K projection (N=2048) and transposed V projection
    gemm_kernel<0><<<dim3(32, 16), blk, 0, stream>>>(xn1, WqkT, QKb, nullptr, nullptr, 2048, DM, 1.0f);
    gemm_kernel<4><<<dim3(32, 8),  blk, 0, stream>>>(xn1, WvT,  VTg, nullptr, nullptr, DM, DM, 1.0f);

    attn_kernel<<<dim3(16, 32), dim3(512), 0, stream>>>(QKb, VTg, attno);

    gemm_kernel<1><<<dim3(32, 8), blk, 0, stream>>>(attno, WoT, x2, nullptr, x, DM, DM, 1.0f);

    ln_kernel<<<dim3(MT), blk, 0, stream>>>(x2, ln2g, ln2b, h2);

    gemm_kernel<2><<<dim3(32, 32), blk, 0, stream>>>(h2, W1T, ffa, b1, nullptr, DFF, DM, 1.0f);
    gemm_kernel<3><<<dim3(32, 8), blk, 0, stream>>>(ffa, W2T, out, b2, x2, DM, DFF, 1.0f);
}

// Round 4
// 327.897 us; speedup vs baseline: 1.1422x; 1.0584x over previous
//
#include <hip/hip_runtime.h>
#include <cstdint>
#include <cstddef>

#define DEV __device__ __forceinline__

typedef __attribute__((ext_vector_type(8))) __bf16 bf16x8;
typedef __attribute__((ext_vector_type(4))) float f32x4;
typedef __attribute__((ext_vector_type(8))) unsigned short u16x8;

typedef const __attribute__((address_space(1))) void gld_gv;
typedef __attribute__((address_space(3))) void gld_sv;

static constexpr int SEQ = 2048, BAT = 2, DM = 1024, DFF = 4096;
static constexpr int MT = BAT * SEQ;  // 4096 rows total
static constexpr float LOG2E = 1.44269504088896340736f;

DEV unsigned short f2bf_bits(float f) {
    uint32_t u = __builtin_bit_cast(uint32_t, f);
    return (unsigned short)((u + 0x7FFFu + ((u >> 16) & 1u)) >> 16);
}

DEV void gload16(const void* g, void* s) {
    __builtin_amdgcn_global_load_lds((gld_gv*)g, (gld_sv*)s, 16, 0, 0);
}

// ---------------- weight transpose + fp32->bf16 convert (+scale) -----------
// W [K][N] f32  ->  WT [N][K] bf16 * scale.  grid (K/64, N/64), block 256.
__global__ __launch_bounds__(256) void wtrans_kernel(const float* __restrict__ W,
        unsigned short* __restrict__ WT, int K, int N, float scale)
{
    __shared__ float tile[64][65];
    const int k0 = blockIdx.x * 64, n0 = blockIdx.y * 64;
    const int t = threadIdx.x, r = t >> 6, c = t & 63;
    #pragma unroll
    for (int p = 0; p < 16; ++p)
        tile[p * 4 + r][c] = W[(size_t)(k0 + p * 4 + r) * N + n0 + c];
    __syncthreads();
    #pragma unroll
    for (int p = 0; p < 16; ++p)
        WT[(size_t)(n0 + p * 4 + r) * K + k0 + c] = f2bf_bits(tile[c][p * 4 + r] * scale);
}

// ---------------- LayerNorm (f32 in -> bf16 out) ----------------
__global__ __launch_bounds__(256) void ln_kernel(const float* __restrict__ x,
        const float* __restrict__ gw, const float* __restrict__ bw,
        unsigned short* __restrict__ y)
{
    const int row = blockIdx.x, t = threadIdx.x;
    const float* xr = x + (size_t)row * DM;
    float4 v = *(const float4*)(xr + t * 4);
    float s = v.x + v.y + v.z + v.w;
    float q = v.x * v.x + v.y * v.y + v.z * v.z + v.w * v.w;
    #pragma unroll
    for (int m = 1; m < 64; m <<= 1) { s += __shfl_xor(s, m); q += __shfl_xor(q, m); }
    __shared__ float red[8];
    const int w = t >> 6;
    if ((t & 63) == 0) { red[w] = s; red[4 + w] = q; }
    __syncthreads();
    s = red[0] + red[1] + red[2] + red[3];
    q = red[4] + red[5] + red[6] + red[7];
    const float mu = s * (1.0f / DM);
    const float rstd = rsqrtf(q * (1.0f / DM) - mu * mu + 1e-5f);
    float4 g4 = *(const float4*)(gw + t * 4);
    float4 b4 = *(const float4*)(bw + t * 4);
    short4 o;
    o.x = (short)f2bf_bits((v.x - mu) * rstd * g4.x + b4.x);
    o.y = (short)f2bf_bits((v.y - mu) * rstd * g4.y + b4.y);
    o.z = (short)f2bf_bits((v.z - mu) * rstd * g4.z + b4.z);
    o.w = (short)f2bf_bits((v.w - mu) * rstd * g4.w + b4.w);
    *(short4*)(y + (size_t)row * DM + t * 4) = o;
}

// ---------------- GEMM: C[M][N] = A[M][K] @ B, BT[N][K] given (both bf16) ---
// EPI 0: bf16 out, *scale      1: f32 out + res     2: +bias, GELU, bf16
// EPI 3: +bias +res, f32       4: bf16 out TRANSPOSED per-head (V^T producer)
template<int EPI>
__global__ __launch_bounds__(256, 2) void gemm_kernel(
    const unsigned short* __restrict__ A, const unsigned short* __restrict__ BT,
    void* __restrict__ Cp, const float* __restrict__ bias,
    const float* __restrict__ res, int Nsz, int Ksz, float scale)
{
    __shared__ alignas(16) unsigned short ldsA[128 * 64];
    __shared__ alignas(16) unsigned short ldsB[128 * 64];
    const int t = threadIdx.x, l = t & 63, w = t >> 6;
    const int wm = w >> 1, wn = w & 1, lr = l & 15, lg = l >> 4;
    const int bm = blockIdx.x, bn = blockIdx.y;

    f32x4 acc[4][4] = {};

    const int srow = t >> 3, scol = (t & 7) * 8;  // elements
    const unsigned short* Ab = A + (size_t)(bm * 128 + srow) * Ksz + scol;
    const unsigned short* Bb = BT + (size_t)(bn * 128 + srow) * Ksz + scol;
    char* la = (char*)ldsA;
    char* lb = (char*)ldsB;

    for (int k0 = 0; k0 < Ksz; k0 += 64) {
        __syncthreads();
        #pragma unroll
        for (int p = 0; p < 4; ++p) {
            gload16(Ab + (size_t)(p * 32) * Ksz + k0, la + p * 4096 + t * 16);
            gload16(Bb + (size_t)(p * 32) * Ksz + k0, lb + p * 4096 + t * 16);
        }
        __syncthreads();
        #pragma unroll
        for (int ks = 0; ks < 2; ++ks) {
            bf16x8 af[4], bfr[4];
            #pragma unroll
            for (int i = 0; i < 4; ++i) {
                af[i]  = *(const bf16x8*)(la + (wm * 64 + i * 16 + lr) * 128 + ks * 64 + lg * 16);
                bfr[i] = *(const bf16x8*)(lb + (wn * 64 + i * 16 + lr) * 128 + ks * 64 + lg * 16);
            }
            #pragma unroll
            for (int mb = 0; mb < 4; ++mb)
                #pragma unroll
                for (int nb = 0; nb < 4; ++nb) {
                    if (EPI == 4)  // swapped operands -> transposed output tile
                        acc[mb][nb] = __builtin_amdgcn_mfma_f32_16x16x32_bf16(
                            bfr[nb], af[mb], acc[mb][nb], 0, 0, 0);
                    else
                        acc[mb][nb] = __builtin_amdgcn_mfma_f32_16x16x32_bf16(
                            af[mb], bfr[nb], acc[mb][nb], 0, 0, 0);
                }
        }
    }

    const int rb = bm * 128 + wm * 64, cb = bn * 128 + wn * 64;
    #pragma unroll
    for (int mb = 0; mb < 4; ++mb)
        #pragma unroll
        for (int nb = 0; nb < 4; ++nb)
            #pragma unroll
            for (int r = 0; r < 4; ++r) {
                float v = acc[mb][nb][r];
                if (EPI == 4) {
                    const int xrow = rb + mb * 16 + lr;          // token row
                    const int feat = cb + nb * 16 + lg * 4 + r;  // output feature
                    const int bb = xrow >> 11, s = xrow & (SEQ - 1);
                    ((unsigned short*)Cp)[((size_t)bb * DM + feat) * SEQ + s] = f2bf_bits(v);
                    continue;
                }
                const int row = rb + mb * 16 + lg * 4 + r;
                const int col = cb + nb * 16 + lr;
                const size_t idx = (size_t)row * Nsz + col;
                if (EPI == 0) {
                    ((unsigned short*)Cp)[idx] = f2bf_bits(v * scale);
                } else if (EPI == 1) {
                    ((float*)Cp)[idx] = v + res[idx];
                } else if (EPI == 2) {
                    float xx = v + bias[col];
                    ((unsigned short*)Cp)[idx] =
                        f2bf_bits(0.5f * xx * (1.0f + erff(xx * 0.70710678118654752f)));
                } else {
                    ((float*)Cp)[idx] = v + bias[col] + res[idx];
                }
            }
}

// ---------------- causal flash attention (double-buffered, KVB=128) --------
// QKg: [B][S][2048] bf16 (Q | K fused, Q pre-scaled 1/8), head h at cols h*64 / 1024+h*64.
// VTg: [B][DM][S] bf16 (V transposed per head).
// Og:  [B][S][DM] bf16.
// grid (16 qtiles, 32 bh), block 512 (8 waves, 16 q-rows each; QBLK=128, KVB=128).
// Tiles staged swizzled: lds 16B-chunk c of row r holds global chunk c^(r&mask).
__global__ __launch_bounds__(512, 4) void attn_kernel(
    const unsigned short* __restrict__ QKg, const unsigned short* __restrict__ VTg,
    unsigned short* __restrict__ Og)
{
    __shared__ alignas(16) unsigned short ldsK[2][128 * 64];
    __shared__ alignas(16) unsigned short ldsVT[2][64 * 128];
    const int t = threadIdx.x, l = t & 63, w = t >> 6;
    const int lr = l & 15, lg = l >> 4;
    const int qt = (int)gridDim.x - 1 - blockIdx.x;  // longest blocks first
    const int bh = blockIdx.y;
    const int b = bh >> 4, h = bh & 15;
    const unsigned short* Qbase = QKg + (size_t)b * SEQ * 2048 + h * 64;
    const unsigned short* Kbase = Qbase + 1024;
    const unsigned short* Vbase = VTg + (size_t)b * DM * SEQ + (size_t)(h * 64) * SEQ;

    const int wq0 = qt * 128 + w * 16;   // wave's first q row
    const int qrow = wq0 + lr;           // this lane's q row
    bf16x8 qf[2];
    #pragma unroll
    for (int ks = 0; ks < 2; ++ks)
        qf[ks] = *(const bf16x8*)(Qbase + (size_t)qrow * 2048 + ks * 32 + lg * 8);

    float m_run = -1e30f, l_run = 0.0f;
    f32x4 oacc[4] = {};

    // staging: per thread 2 chunks of K (128x64) and 2 of VT (64x128)
    const int kci[2] = { t, t + 512 };

    const int nkt = qt + 1;

    // prologue: stage tile 0 into buf 0
    #pragma unroll
    for (int p = 0; p < 2; ++p) {
        const int ci = kci[p];
        const int kr = ci >> 3, kc = (ci & 7) ^ (kr & 7);
        gload16(Kbase + (size_t)kr * 2048 + kc * 8, (char*)ldsK[0] + ci * 16);
        const int vr = ci >> 4, vc = (ci & 15) ^ (vr & 15);
        gload16(Vbase + (size_t)vr * SEQ + vc * 8, (char*)ldsVT[0] + ci * 16);
    }
    asm volatile("s_waitcnt vmcnt(0)" ::: "memory");
    __builtin_amdgcn_s_barrier();

    for (int kt = 0; kt < nkt; ++kt) {
        const int cur = kt & 1;
        // issue next-tile staging into the other buffer (safe: separated from
        // its readers by the barrier at the end of the previous iteration)
        if (kt + 1 < nkt) {
            #pragma unroll
            for (int p = 0; p < 2; ++p) {
                const int ci = kci[p];
                const int kr = ci >> 3, kc = (ci & 7) ^ (kr & 7);
                gload16(Kbase + (size_t)((kt + 1) * 128 + kr) * 2048 + kc * 8,
                        (char*)ldsK[cur ^ 1] + ci * 16);
                const int vr = ci >> 4, vc = (ci & 15) ^ (vr & 15);
                gload16(Vbase + (size_t)vr * SEQ + (kt + 1) * 128 + vc * 8,
                        (char*)ldsVT[cur ^ 1] + ci * 16);
            }
        }
        const char* lk = (const char*)ldsK[cur];
        const char* lv = (const char*)ldsVT[cur];

        // S^T = K . Q^T : lane holds q = lr, key = mb*16 + lg*4 + reg
        __builtin_amdgcn_s_setprio(1);
        f32x4 st[8] = {};
        #pragma unroll
        for (int ks = 0; ks < 2; ++ks)
            #pragma unroll
            for (int mb = 0; mb < 8; ++mb) {
                bf16x8 kf = *(const bf16x8*)(lk + (mb * 16 + lr) * 128
                                             + (((ks * 4 + lg) ^ (lr & 7)) * 16));
                st[mb] = __builtin_amdgcn_mfma_f32_16x16x32_bf16(kf, qf[ks], st[mb], 0, 0, 0);
            }
        __builtin_amdgcn_s_setprio(0);

        const int kt0 = kt * 128;
        if (kt0 + 127 > wq0) {  // wave-uniform: diagonal tile
            #pragma unroll
            for (int mb = 0; mb < 8; ++mb)
                #pragma unroll
                for (int r = 0; r < 4; ++r)
                    if (kt0 + mb * 16 + lg * 4 + r > qrow) st[mb][r] = -1e30f;
        }

        float mt = -1e30f;
        #pragma unroll
        for (int mb = 0; mb < 8; ++mb)
            mt = fmaxf(mt, fmaxf(fmaxf(st[mb][0], st[mb][1]), fmaxf(st[mb][2], st[mb][3])));
        mt = fmaxf(mt, __shfl_xor(mt, 16));
        mt = fmaxf(mt, __shfl_xor(mt, 32));

        // defer-max (T13): only rescale when tile max exceeds running max + 8
        if (!__all(mt <= m_run + 8.0f)) {
            const float m_new = fmaxf(m_run, mt);
            const float alpha = exp2f((m_run - m_new) * LOG2E);
            l_run *= alpha;
            #pragma unroll
            for (int j = 0; j < 4; ++j) {
                const float aj = __shfl(alpha, lg * 4 + j);
                #pragma unroll
                for (int nb = 0; nb < 4; ++nb) oacc[nb][j] *= aj;
            }
            m_run = m_new;
        }

        const float nml = m_run * LOG2E;
        float rs = 0.0f;
        #pragma unroll
        for (int mb = 0; mb < 8; ++mb)
            #pragma unroll
            for (int r = 0; r < 4; ++r) {
                const float p = exp2f(fmaf(st[mb][r], LOG2E, -nml));
                st[mb][r] = p;
                rs += p;
            }
        rs += __shfl_xor(rs, 16);
        rs += __shfl_xor(rs, 32);
        l_run += rs;

        // P -> A-frags in-register. Slot map f(lg,j) = 16*(j>>2) + lg*4 + (j&3),
        // keys = 32*ks + f.
        bf16x8 pa[4];
        #pragma unroll
        for (int ks = 0; ks < 4; ++ks)
            #pragma unroll
            for (int j = 0; j < 4; ++j) {
                pa[ks][j]     = (__bf16)st[2 * ks][j];
                pa[ks][j + 4] = (__bf16)st[2 * ks + 1][j];
            }

        // V B-frags from swizzled VT rows: slot j holds V[32ks+f(lg,j)][n=16nb+lr]
        __builtin_amdgcn_s_setprio(1);
        #pragma unroll
        for (int ks = 0; ks < 4; ++ks)
            #pragma unroll
            for (int nb = 0; nb < 4; ++nb) {
                const int n = nb * 16 + lr;
                union { bf16x8 v; uint64_t d[2]; } vb;
                vb.d[0] = *(const uint64_t*)(lv + n * 256
                            + (((4 * ks + (lg >> 1)) ^ (n & 15)) * 16) + 8 * (lg & 1));
                vb.d[1] = *(const uint64_t*)(lv + n * 256
                            + (((4 * ks + 2 + (lg >> 1)) ^ (n & 15)) * 16) + 8 * (lg & 1));
                oacc[nb] = __builtin_amdgcn_mfma_f32_16x16x32_bf16(pa[ks], vb.v, oacc[nb], 0, 0, 0);
            }
        __builtin_amdgcn_s_setprio(0);

        // single drain + barrier per tile: next tile's loads are now complete
        asm volatile("s_waitcnt vmcnt(0)" ::: "memory");
        __builtin_amdgcn_s_barrier();
    }

    unsigned short* Ob = Og + (size_t)b * SEQ * DM + h * 64;
    #pragma unroll
    for (int j = 0; j < 4; ++j) {
        const float inv = 1.0f / __shfl(l_run, lg * 4 + j);
        const int row = wq0 + lg * 4 + j;
        #pragma unroll
        for (int nb = 0; nb < 4; ++nb)
            Ob[(size_t)row * DM + nb * 16 + lr] = f2bf_bits(oacc[nb][j] * inv);
    }
}

// ---------------- launcher ----------------
extern "C" void kernel_launch(void* const* d_in, const int* in_sizes, int n_in,
                              void* d_out, int out_size, void* d_ws, size_t ws_size,
                              hipStream_t stream) {
    (void)in_sizes; (void)n_in; (void)out_size; (void)ws_size;
    const float* x    = (const float*)d_in[0];
    const float* Wq   = (const float*)d_in[1];
    const float* Wk   = (const float*)d_in[2];
    const float* Wv   = (const float*)d_in[3];
    const float* Wo   = (const float*)d_in[4];
    const float* ln1g = (const float*)d_in[5];
    const float* ln1b = (const float*)d_in[6];
    const float* ln2g = (const float*)d_in[7];
    const float* ln2b = (const float*)d_in[8];
    const float* W1   = (const float*)d_in[9];
    const float* b1   = (const float*)d_in[10];
    const float* W2   = (const float*)d_in[11];
    const float* b2   = (const float*)d_in[12];
    float* out = (float*)d_out;

    char* ws = (char*)d_ws;
    const size_t MB = 1ull << 20;
    unsigned short* xn1   = (unsigned short*)(ws + 0 * MB);   // 8 MB [4096][1024]
    unsigned short* QKb   = (unsigned short*)(ws + 8 * MB);   // 16 MB [2][2048][2048]
    unsigned short* VTg   = (unsigned short*)(ws + 24 * MB);  // 8 MB [2][1024][2048]
    unsigned short* ffa   = (unsigned short*)(ws + 0 * MB);   // 32 MB (aliases xn1/QKb/VTg)
    unsigned short* attno = (unsigned short*)(ws + 32 * MB);  // 8 MB
    float*          x2    = (float*)(ws + 40 * MB);           // 16 MB
    unsigned short* h2    = (unsigned short*)(ws + 56 * MB);  // 8 MB
    unsigned short* WqkT  = (unsigned short*)(ws + 64 * MB);  // 4 MB [2048][1024]
    unsigned short* WvT   = (unsigned short*)(ws + 68 * MB);  // 2 MB
    unsigned short* WoT   = (unsigned short*)(ws + 70 * MB);  // 2 MB
    unsigned short* W1T   = (unsigned short*)(ws + 72 * MB);  // 8 MB
    unsigned short* W2T   = (unsigned short*)(ws + 80 * MB);  // 8 MB  (total 88 MB)

    dim3 blk(256);
    wtrans_kernel<<<dim3(16, 16), blk, 0, stream>>>(Wq, WqkT, DM, DM, 0.125f);
    wtrans_kernel<<<dim3(16, 16), blk, 0, stream>>>(Wk, WqkT + DM * DM, DM, DM, 1.0f);
    wtrans_kernel<<<dim3(16, 16), blk, 0, stream>>>(Wv, WvT, DM, DM, 1.0f);
    wtrans_kernel<<<dim3(16, 16), blk, 0, stream>>>(Wo, WoT, DM, DM, 1.0f);
    wtrans_kernel<<<dim3(16, 64), blk, 0, stream>>>(W1, W1T, DM, DFF, 1.0f);
    wtrans_kernel<<<dim3(64, 16), blk, 0, stream>>>(W2, W2T, DFF, DM, 1.0f);

    ln_kernel<<<dim3(MT), blk, 0, stream>>>(x, ln1g, ln1b, xn1);

    // fused Q|K projection (N=2048) and transposed V projection
    gemm_kernel<0><<<dim3(32, 16), blk, 0, stream>>>(xn1, WqkT, QKb, nullptr, nullptr, 2048, DM, 1.0f);
    gemm_kernel<4><<<dim3(32, 8),  blk, 0, stream>>>(xn1, WvT,  VTg, nullptr, nullptr, DM, DM, 1.0f);

    attn_kernel<<<dim3(16, 32), dim3(512), 0, stream>>>(QKb, VTg, attno);

    gemm_kernel<1><<<dim3(32, 8), blk, 0, stream>>>(attno, WoT, x2, nullptr, x, DM, DM, 1.0f);

    ln_kernel<<<dim3(MT), blk, 0, stream>>>(x2, ln2g, ln2b, h2);

    gemm_kernel<2><<<dim3(32, 32), blk, 0, stream>>>(h2, W1T, ffa, b1, nullptr, DFF, DM, 1.0f);
    gemm_kernel<3><<<dim3(32, 8), blk, 0, stream>>>(ffa, W2T, out, b2, x2, DM, DFF, 1.0f);
}

// Round 5
// 318.230 us; speedup vs baseline: 1.1769x; 1.0304x over previous
//
#include <hip/hip_runtime.h>
#include <cstdint>
#include <cstddef>

#define DEV __device__ __forceinline__

typedef __attribute__((ext_vector_type(8))) __bf16 bf16x8;
typedef __attribute__((ext_vector_type(4))) float f32x4;
typedef __attribute__((ext_vector_type(8))) unsigned short u16x8;

typedef const __attribute__((address_space(1))) void gld_gv;
typedef __attribute__((address_space(3))) void gld_sv;

static constexpr int SEQ = 2048, BAT = 2, DM = 1024, DFF = 4096;
static constexpr int MT = BAT * SEQ;  // 4096 rows total
static constexpr float LOG2E = 1.44269504088896340736f;

DEV unsigned short f2bf_bits(float f) {
    uint32_t u = __builtin_bit_cast(uint32_t, f);
    return (unsigned short)((u + 0x7FFFu + ((u >> 16) & 1u)) >> 16);
}

DEV void gload16(const void* g, void* s) {
    __builtin_amdgcn_global_load_lds((gld_gv*)g, (gld_sv*)s, 16, 0, 0);
}

// ---------------- weight transpose + fp32->bf16 convert (+scale) -----------
// W [K][N] f32  ->  WT [N][K] bf16 * scale.  grid (K/64, N/64), block 256.
__global__ __launch_bounds__(256) void wtrans_kernel(const float* __restrict__ W,
        unsigned short* __restrict__ WT, int K, int N, float scale)
{
    __shared__ float tile[64][65];
    const int k0 = blockIdx.x * 64, n0 = blockIdx.y * 64;
    const int t = threadIdx.x, r = t >> 6, c = t & 63;
    #pragma unroll
    for (int p = 0; p < 16; ++p)
        tile[p * 4 + r][c] = W[(size_t)(k0 + p * 4 + r) * N + n0 + c];
    __syncthreads();
    #pragma unroll
    for (int p = 0; p < 16; ++p)
        WT[(size_t)(n0 + p * 4 + r) * K + k0 + c] = f2bf_bits(tile[c][p * 4 + r] * scale);
}

// ---------------- LayerNorm (f32 in -> bf16 out) ----------------
__global__ __launch_bounds__(256) void ln_kernel(const float* __restrict__ x,
        const float* __restrict__ gw, const float* __restrict__ bw,
        unsigned short* __restrict__ y)
{
    const int row = blockIdx.x, t = threadIdx.x;
    const float* xr = x + (size_t)row * DM;
    float4 v = *(const float4*)(xr + t * 4);
    float s = v.x + v.y + v.z + v.w;
    float q = v.x * v.x + v.y * v.y + v.z * v.z + v.w * v.w;
    #pragma unroll
    for (int m = 1; m < 64; m <<= 1) { s += __shfl_xor(s, m); q += __shfl_xor(q, m); }
    __shared__ float red[8];
    const int w = t >> 6;
    if ((t & 63) == 0) { red[w] = s; red[4 + w] = q; }
    __syncthreads();
    s = red[0] + red[1] + red[2] + red[3];
    q = red[4] + red[5] + red[6] + red[7];
    const float mu = s * (1.0f / DM);
    const float rstd = rsqrtf(q * (1.0f / DM) - mu * mu + 1e-5f);
    float4 g4 = *(const float4*)(gw + t * 4);
    float4 b4 = *(const float4*)(bw + t * 4);
    short4 o;
    o.x = (short)f2bf_bits((v.x - mu) * rstd * g4.x + b4.x);
    o.y = (short)f2bf_bits((v.y - mu) * rstd * g4.y + b4.y);
    o.z = (short)f2bf_bits((v.z - mu) * rstd * g4.z + b4.z);
    o.w = (short)f2bf_bits((v.w - mu) * rstd * g4.w + b4.w);
    *(short4*)(y + (size_t)row * DM + t * 4) = o;
}

// ---------------- GEMM: C[M][N] = A[M][K] @ B, BT[N][K] given (both bf16) ---
// 2-phase double-buffered (T3-minimum): issue next-tile global_load_lds, compute
// current tile, single counted drain + raw barrier per K-step.
// BM=128, BK=64, BN in {128, 64}. BN=128: 4 waves 2x2 of 64x64. BN=64: 4 waves
// 4x1 of 32x64 (for N=1024 GEMMs: doubles grid to 512 blocks, 3 blocks/CU).
// EPI 0: bf16 out, *scale      1: f32 out + res     2: +bias, GELU, bf16
// EPI 3: +bias +res, f32       4: bf16 out TRANSPOSED per-head (V^T producer)
template<int EPI, int BN>
__global__ __launch_bounds__(256, (BN == 128) ? 2 : 3) void gemm_kernel(
    const unsigned short* __restrict__ A, const unsigned short* __restrict__ BT,
    void* __restrict__ Cp, const float* __restrict__ bias,
    const float* __restrict__ res, int Nsz, int Ksz, float scale)
{
    constexpr int BM = 128, BK = 64;
    constexpr int MREP = (BN == 128) ? 4 : 2;   // 16-row frags per wave (M)
    constexpr int WM = MREP * 16;               // wave rows: 64 or 32
    constexpr int BCH = BN / 32;                // per-thread B chunks
    __shared__ alignas(16) unsigned short ldsA[2][BM * BK];
    __shared__ alignas(16) unsigned short ldsB[2][BN * BK];
    const int t = threadIdx.x, l = t & 63, w = t >> 6;
    const int wm = (BN == 128) ? (w >> 1) : w;
    const int wn = (BN == 128) ? (w & 1) : 0;
    const int lr = l & 15, lg = l >> 4;
    const int bm = blockIdx.x, bn = blockIdx.y;

    f32x4 acc[MREP][4] = {};

    const int srow = t >> 3, scol = (t & 7) * 8;  // elements
    const unsigned short* Ab = A + (size_t)(bm * BM + srow) * Ksz + scol;
    const unsigned short* Bb = BT + (size_t)(bn * BN + srow) * Ksz + scol;

    const int nk = Ksz / BK;

    // prologue: stage tile 0 into buf 0
    #pragma unroll
    for (int p = 0; p < 4; ++p)
        gload16(Ab + (size_t)(p * 32) * Ksz, (char*)ldsA[0] + (t + p * 256) * 16);
    #pragma unroll
    for (int p = 0; p < BCH; ++p)
        gload16(Bb + (size_t)(p * 32) * Ksz, (char*)ldsB[0] + (t + p * 256) * 16);
    asm volatile("s_waitcnt vmcnt(0)" ::: "memory");
    __builtin_amdgcn_s_barrier();

    for (int kt = 0; kt < nk; ++kt) {
        const int cur = kt & 1;
        if (kt + 1 < nk) {  // issue next-tile staging into the other buffer
            const int k0 = (kt + 1) * BK;
            #pragma unroll
            for (int p = 0; p < 4; ++p)
                gload16(Ab + (size_t)(p * 32) * Ksz + k0,
                        (char*)ldsA[cur ^ 1] + (t + p * 256) * 16);
            #pragma unroll
            for (int p = 0; p < BCH; ++p)
                gload16(Bb + (size_t)(p * 32) * Ksz + k0,
                        (char*)ldsB[cur ^ 1] + (t + p * 256) * 16);
        }
        const char* la = (const char*)ldsA[cur];
        const char* lb = (const char*)ldsB[cur];
        __builtin_amdgcn_s_setprio(1);
        #pragma unroll
        for (int ks = 0; ks < 2; ++ks) {
            bf16x8 af[MREP], bfr[4];
            #pragma unroll
            for (int i = 0; i < MREP; ++i)
                af[i] = *(const bf16x8*)(la + (wm * WM + i * 16 + lr) * 128 + ks * 64 + lg * 16);
            #pragma unroll
            for (int i = 0; i < 4; ++i)
                bfr[i] = *(const bf16x8*)(lb + (wn * 64 + i * 16 + lr) * 128 + ks * 64 + lg * 16);
            #pragma unroll
            for (int mb = 0; mb < MREP; ++mb)
                #pragma unroll
                for (int nb = 0; nb < 4; ++nb) {
                    if (EPI == 4)  // swapped operands -> transposed output tile
                        acc[mb][nb] = __builtin_amdgcn_mfma_f32_16x16x32_bf16(
                            bfr[nb], af[mb], acc[mb][nb], 0, 0, 0);
                    else
                        acc[mb][nb] = __builtin_amdgcn_mfma_f32_16x16x32_bf16(
                            af[mb], bfr[nb], acc[mb][nb], 0, 0, 0);
                }
        }
        __builtin_amdgcn_s_setprio(0);
        // counted drain: next tile's loads have been hidden under this compute
        asm volatile("s_waitcnt vmcnt(0)" ::: "memory");
        __builtin_amdgcn_s_barrier();
    }

    const int rb = bm * BM + wm * WM, cb = bn * BN + wn * 64;
    #pragma unroll
    for (int mb = 0; mb < MREP; ++mb)
        #pragma unroll
        for (int nb = 0; nb < 4; ++nb)
            #pragma unroll
            for (int r = 0; r < 4; ++r) {
                float v = acc[mb][nb][r];
                if (EPI == 4) {
                    const int xrow = rb + mb * 16 + lr;          // token row
                    const int feat = cb + nb * 16 + lg * 4 + r;  // output feature
                    const int bb = xrow >> 11, s = xrow & (SEQ - 1);
                    ((unsigned short*)Cp)[((size_t)bb * DM + feat) * SEQ + s] = f2bf_bits(v);
                    continue;
                }
                const int row = rb + mb * 16 + lg * 4 + r;
                const int col = cb + nb * 16 + lr;
                const size_t idx = (size_t)row * Nsz + col;
                if (EPI == 0) {
                    ((unsigned short*)Cp)[idx] = f2bf_bits(v * scale);
                } else if (EPI == 1) {
                    ((float*)Cp)[idx] = v + res[idx];
                } else if (EPI == 2) {
                    float xx = v + bias[col];
                    ((unsigned short*)Cp)[idx] =
                        f2bf_bits(0.5f * xx * (1.0f + erff(xx * 0.70710678118654752f)));
                } else {
                    ((float*)Cp)[idx] = v + bias[col] + res[idx];
                }
            }
}

// ---------------- causal flash attention (double-buffered, KVB=128) --------
// QKg: [B][S][2048] bf16 (Q | K fused, Q pre-scaled 1/8), head h at cols h*64 / 1024+h*64.
// VTg: [B][DM][S] bf16 (V transposed per head).
// Og:  [B][S][DM] bf16.
// grid (16 qtiles, 32 bh), block 512 (8 waves, 16 q-rows each; QBLK=128, KVB=128).
// Tiles staged swizzled: lds 16B-chunk c of row r holds global chunk c^(r&mask).
__global__ __launch_bounds__(512, 4) void attn_kernel(
    const unsigned short* __restrict__ QKg, const unsigned short* __restrict__ VTg,
    unsigned short* __restrict__ Og)
{
    __shared__ alignas(16) unsigned short ldsK[2][128 * 64];
    __shared__ alignas(16) unsigned short ldsVT[2][64 * 128];
    const int t = threadIdx.x, l = t & 63, w = t >> 6;
    const int lr = l & 15, lg = l >> 4;
    const int qt = (int)gridDim.x - 1 - blockIdx.x;  // longest blocks first
    const int bh = blockIdx.y;
    const int b = bh >> 4, h = bh & 15;
    const unsigned short* Qbase = QKg + (size_t)b * SEQ * 2048 + h * 64;
    const unsigned short* Kbase = Qbase + 1024;
    const unsigned short* Vbase = VTg + (size_t)b * DM * SEQ + (size_t)(h * 64) * SEQ;

    const int wq0 = qt * 128 + w * 16;   // wave's first q row
    const int qrow = wq0 + lr;           // this lane's q row
    bf16x8 qf[2];
    #pragma unroll
    for (int ks = 0; ks < 2; ++ks)
        qf[ks] = *(const bf16x8*)(Qbase + (size_t)qrow * 2048 + ks * 32 + lg * 8);

    float m_run = -1e30f, l_run = 0.0f;
    f32x4 oacc[4] = {};

    // staging: per thread 2 chunks of K (128x64) and 2 of VT (64x128)
    const int kci[2] = { t, t + 512 };

    const int nkt = qt + 1;

    // prologue: stage tile 0 into buf 0
    #pragma unroll
    for (int p = 0; p < 2; ++p) {
        const int ci = kci[p];
        const int kr = ci >> 3, kc = (ci & 7) ^ (kr & 7);
        gload16(Kbase + (size_t)kr * 2048 + kc * 8, (char*)ldsK[0] + ci * 16);
        const int vr = ci >> 4, vc = (ci & 15) ^ (vr & 15);
        gload16(Vbase + (size_t)vr * SEQ + vc * 8, (char*)ldsVT[0] + ci * 16);
    }
    asm volatile("s_waitcnt vmcnt(0)" ::: "memory");
    __builtin_amdgcn_s_barrier();

    for (int kt = 0; kt < nkt; ++kt) {
        const int cur = kt & 1;
        // issue next-tile staging into the other buffer (safe: separated from
        // its readers by the barrier at the end of the previous iteration)
        if (kt + 1 < nkt) {
            #pragma unroll
            for (int p = 0; p < 2; ++p) {
                const int ci = kci[p];
                const int kr = ci >> 3, kc = (ci & 7) ^ (kr & 7);
                gload16(Kbase + (size_t)((kt + 1) * 128 + kr) * 2048 + kc * 8,
                        (char*)ldsK[cur ^ 1] + ci * 16);
                const int vr = ci >> 4, vc = (ci & 15) ^ (vr & 15);
                gload16(Vbase + (size_t)vr * SEQ + (kt + 1) * 128 + vc * 8,
                        (char*)ldsVT[cur ^ 1] + ci * 16);
            }
        }
        const char* lk = (const char*)ldsK[cur];
        const char* lv = (const char*)ldsVT[cur];

        // S^T = K . Q^T : lane holds q = lr, key = mb*16 + lg*4 + reg
        __builtin_amdgcn_s_setprio(1);
        f32x4 st[8] = {};
        #pragma unroll
        for (int ks = 0; ks < 2; ++ks)
            #pragma unroll
            for (int mb = 0; mb < 8; ++mb) {
                bf16x8 kf = *(const bf16x8*)(lk + (mb * 16 + lr) * 128
                                             + (((ks * 4 + lg) ^ (lr & 7)) * 16));
                st[mb] = __builtin_amdgcn_mfma_f32_16x16x32_bf16(kf, qf[ks], st[mb], 0, 0, 0);
            }
        __builtin_amdgcn_s_setprio(0);

        const int kt0 = kt * 128;
        if (kt0 + 127 > wq0) {  // wave-uniform: diagonal tile
            #pragma unroll
            for (int mb = 0; mb < 8; ++mb)
                #pragma unroll
                for (int r = 0; r < 4; ++r)
                    if (kt0 + mb * 16 + lg * 4 + r > qrow) st[mb][r] = -1e30f;
        }

        float mt = -1e30f;
        #pragma unroll
        for (int mb = 0; mb < 8; ++mb)
            mt = fmaxf(mt, fmaxf(fmaxf(st[mb][0], st[mb][1]), fmaxf(st[mb][2], st[mb][3])));
        mt = fmaxf(mt, __shfl_xor(mt, 16));
        mt = fmaxf(mt, __shfl_xor(mt, 32));

        // defer-max (T13): only rescale when tile max exceeds running max + 8
        if (!__all(mt <= m_run + 8.0f)) {
            const float m_new = fmaxf(m_run, mt);
            const float alpha = exp2f((m_run - m_new) * LOG2E);
            l_run *= alpha;
            #pragma unroll
            for (int j = 0; j < 4; ++j) {
                const float aj = __shfl(alpha, lg * 4 + j);
                #pragma unroll
                for (int nb = 0; nb < 4; ++nb) oacc[nb][j] *= aj;
            }
            m_run = m_new;
        }

        const float nml = m_run * LOG2E;
        float rs = 0.0f;
        #pragma unroll
        for (int mb = 0; mb < 8; ++mb)
            #pragma unroll
            for (int r = 0; r < 4; ++r) {
                const float p = exp2f(fmaf(st[mb][r], LOG2E, -nml));
                st[mb][r] = p;
                rs += p;
            }
        rs += __shfl_xor(rs, 16);
        rs += __shfl_xor(rs, 32);
        l_run += rs;

        // P -> A-frags in-register. Slot map f(lg,j) = 16*(j>>2) + lg*4 + (j&3),
        // keys = 32*ks + f.
        bf16x8 pa[4];
        #pragma unroll
        for (int ks = 0; ks < 4; ++ks)
            #pragma unroll
            for (int j = 0; j < 4; ++j) {
                pa[ks][j]     = (__bf16)st[2 * ks][j];
                pa[ks][j + 4] = (__bf16)st[2 * ks + 1][j];
            }

        // V B-frags from swizzled VT rows: slot j holds V[32ks+f(lg,j)][n=16nb+lr]
        __builtin_amdgcn_s_setprio(1);
        #pragma unroll
        for (int ks = 0; ks < 4; ++ks)
            #pragma unroll
            for (int nb = 0; nb < 4; ++nb) {
                const int n = nb * 16 + lr;
                union { bf16x8 v; uint64_t d[2]; } vb;
                vb.d[0] = *(const uint64_t*)(lv + n * 256
                            + (((4 * ks + (lg >> 1)) ^ (n & 15)) * 16) + 8 * (lg & 1));
                vb.d[1] = *(const uint64_t*)(lv + n * 256
                            + (((4 * ks + 2 + (lg >> 1)) ^ (n & 15)) * 16) + 8 * (lg & 1));
                oacc[nb] = __builtin_amdgcn_mfma_f32_16x16x32_bf16(pa[ks], vb.v, oacc[nb], 0, 0, 0);
            }
        __builtin_amdgcn_s_setprio(0);

        // single drain + barrier per tile: next tile's loads are now complete
        asm volatile("s_waitcnt vmcnt(0)" ::: "memory");
        __builtin_amdgcn_s_barrier();
    }

    unsigned short* Ob = Og + (size_t)b * SEQ * DM + h * 64;
    #pragma unroll
    for (int j = 0; j < 4; ++j) {
        const float inv = 1.0f / __shfl(l_run, lg * 4 + j);
        const int row = wq0 + lg * 4 + j;
        #pragma unroll
        for (int nb = 0; nb < 4; ++nb)
            Ob[(size_t)row * DM + nb * 16 + lr] = f2bf_bits(oacc[nb][j] * inv);
    }
}

// ---------------- launcher ----------------
extern "C" void kernel_launch(void* const* d_in, const int* in_sizes, int n_in,
                              void* d_out, int out_size, void* d_ws, size_t ws_size,
                              hipStream_t stream) {
    (void)in_sizes; (void)n_in; (void)out_size; (void)ws_size;
    const float* x    = (const float*)d_in[0];
    const float* Wq   = (const float*)d_in[1];
    const float* Wk   = (const float*)d_in[2];
    const float* Wv   = (const float*)d_in[3];
    const float* Wo   = (const float*)d_in[4];
    const float* ln1g = (const float*)d_in[5];
    const float* ln1b = (const float*)d_in[6];
    const float* ln2g = (const float*)d_in[7];
    const float* ln2b = (const float*)d_in[8];
    const float* W1   = (const float*)d_in[9];
    const float* b1   = (const float*)d_in[10];
    const float* W2   = (const float*)d_in[11];
    const float* b2   = (const float*)d_in[12];
    float* out = (float*)d_out;

    char* ws = (char*)d_ws;
    const size_t MB = 1ull << 20;
    unsigned short* xn1   = (unsigned short*)(ws + 0 * MB);   // 8 MB [4096][1024]
    unsigned short* QKb   = (unsigned short*)(ws + 8 * MB);   // 16 MB [2][2048][2048]
    unsigned short* VTg   = (unsigned short*)(ws + 24 * MB);  // 8 MB [2][1024][2048]
    unsigned short* ffa   = (unsigned short*)(ws + 0 * MB);   // 32 MB (aliases xn1/QKb/VTg)
    unsigned short* attno = (unsigned short*)(ws + 32 * MB);  // 8 MB
    float*          x2    = (float*)(ws + 40 * MB);           // 16 MB
    unsigned short* h2    = (unsigned short*)(ws + 56 * MB);  // 8 MB
    unsigned short* WqkT  = (unsigned short*)(ws + 64 * MB);  // 4 MB [2048][1024]
    unsigned short* WvT   = (unsigned short*)(ws + 68 * MB);  // 2 MB
    unsigned short* WoT   = (unsigned short*)(ws + 70 * MB);  // 2 MB
    unsigned short* W1T   = (unsigned short*)(ws + 72 * MB);  // 8 MB
    unsigned short* W2T   = (unsigned short*)(ws + 80 * MB);  // 8 MB  (total 88 MB)

    dim3 blk(256);
    wtrans_kernel<<<dim3(16, 16), blk, 0, stream>>>(Wq, WqkT, DM, DM, 0.125f);
    wtrans_kernel<<<dim3(16, 16), blk, 0, stream>>>(Wk, WqkT + DM * DM, DM, DM, 1.0f);
    wtrans_kernel<<<dim3(16, 16), blk, 0, stream>>>(Wv, WvT, DM, DM, 1.0f);
    wtrans_kernel<<<dim3(16, 16), blk, 0, stream>>>(Wo, WoT, DM, DM, 1.0f);
    wtrans_kernel<<<dim3(16, 64), blk, 0, stream>>>(W1, W1T, DM, DFF, 1.0f);
    wtrans_kernel<<<dim3(64, 16), blk, 0, stream>>>(W2, W2T, DFF, DM, 1.0f);

    ln_kernel<<<dim3(MT), blk, 0, stream>>>(x, ln1g, ln1b, xn1);

    // fused Q|K projection (N=2048) and transposed V projection
    gemm_kernel<0, 128><<<dim3(32, 16), blk, 0, stream>>>(xn1, WqkT, QKb, nullptr, nullptr, 2048, DM, 1.0f);
    gemm_kernel<4, 64><<<dim3(32, 16), blk, 0, stream>>>(xn1, WvT, VTg, nullptr, nullptr, DM, DM, 1.0f);

    attn_kernel<<<dim3(16, 32), dim3(512), 0, stream>>>(QKb, VTg, attno);

    gemm_kernel<1, 64><<<dim3(32, 16), blk, 0, stream>>>(attno, WoT, x2, nullptr, x, DM, DM, 1.0f);

    ln_kernel<<<dim3(MT), blk, 0, stream>>>(x2, ln2g, ln2b, h2);

    gemm_kernel<2, 128><<<dim3(32, 32), blk, 0, stream>>>(h2, W1T, ffa, b1, nullptr, DFF, DM, 1.0f);
    gemm_kernel<3, 64><<<dim3(32, 16), blk, 0, stream>>>(ffa, W2T, out, b2, x2, DM, DFF, 1.0f);
}

// Round 7
// 259.591 us; speedup vs baseline: 1.4428x; 1.2259x over previous
//
#include <hip/hip_runtime.h>
#include <cstdint>
#include <cstddef>

#define DEV __device__ __forceinline__

typedef __attribute__((ext_vector_type(8))) __bf16 bf16x8;
typedef __attribute__((ext_vector_type(4))) float f32x4;
typedef __attribute__((ext_vector_type(8))) unsigned short u16x8;

typedef const __attribute__((address_space(1))) void gld_gv;
typedef __attribute__((address_space(3))) void gld_sv;

static constexpr int SEQ = 2048, BAT = 2, DM = 1024, DFF = 4096;
static constexpr int MT = BAT * SEQ;  // 4096 rows total
static constexpr float LOG2E = 1.44269504088896340736f;

DEV unsigned short f2bf_bits(float f) {
    uint32_t u = __builtin_bit_cast(uint32_t, f);
    return (unsigned short)((u + 0x7FFFu + ((u >> 16) & 1u)) >> 16);
}

DEV void gload16(const void* g, void* s) {
    __builtin_amdgcn_global_load_lds((gld_gv*)g, (gld_sv*)s, 16, 0, 0);
}

// ---------------- weight transpose + fp32->bf16 convert (+scale) -----------
__global__ __launch_bounds__(256) void wtrans_kernel(const float* __restrict__ W,
        unsigned short* __restrict__ WT, int K, int N, float scale)
{
    __shared__ float tile[64][65];
    const int k0 = blockIdx.x * 64, n0 = blockIdx.y * 64;
    const int t = threadIdx.x, r = t >> 6, c = t & 63;
    #pragma unroll
    for (int p = 0; p < 16; ++p)
        tile[p * 4 + r][c] = W[(size_t)(k0 + p * 4 + r) * N + n0 + c];
    __syncthreads();
    #pragma unroll
    for (int p = 0; p < 16; ++p)
        WT[(size_t)(n0 + p * 4 + r) * K + k0 + c] = f2bf_bits(tile[c][p * 4 + r] * scale);
}

// ---------------- LayerNorm (f32 in -> bf16 out) ----------------
__global__ __launch_bounds__(256) void ln_kernel(const float* __restrict__ x,
        const float* __restrict__ gw, const float* __restrict__ bw,
        unsigned short* __restrict__ y)
{
    const int row = blockIdx.x, t = threadIdx.x;
    const float* xr = x + (size_t)row * DM;
    float4 v = *(const float4*)(xr + t * 4);
    float s = v.x + v.y + v.z + v.w;
    float q = v.x * v.x + v.y * v.y + v.z * v.z + v.w * v.w;
    #pragma unroll
    for (int m = 1; m < 64; m <<= 1) { s += __shfl_xor(s, m); q += __shfl_xor(q, m); }
    __shared__ float red[8];
    const int w = t >> 6;
    if ((t & 63) == 0) { red[w] = s; red[4 + w] = q; }
    __syncthreads();
    s = red[0] + red[1] + red[2] + red[3];
    q = red[4] + red[5] + red[6] + red[7];
    const float mu = s * (1.0f / DM);
    const float rstd = rsqrtf(q * (1.0f / DM) - mu * mu + 1e-5f);
    float4 g4 = *(const float4*)(gw + t * 4);
    float4 b4 = *(const float4*)(bw + t * 4);
    short4 o;
    o.x = (short)f2bf_bits((v.x - mu) * rstd * g4.x + b4.x);
    o.y = (short)f2bf_bits((v.y - mu) * rstd * g4.y + b4.y);
    o.z = (short)f2bf_bits((v.z - mu) * rstd * g4.z + b4.z);
    o.w = (short)f2bf_bits((v.w - mu) * rstd * g4.w + b4.w);
    *(short4*)(y + (size_t)row * DM + t * 4) = o;
}

// ---------------- GEMM: depth-2 pipelined, counted vmcnt, swizzled LDS -----
// C[M][N] = A[M][K] @ B, with BT[N][K] given (both bf16). BK=64.
// Pipeline: prologue stages tiles 0,1; iter t: vmcnt(TL) [tile t's loads done,
// tile t+1's still in flight] -> barrier -> compute slot t&1 -> barrier ->
// stage tile t+2 into freed slot. Loads never drain to 0 in the loop (T4),
// EXCEPT the last iteration: no tile t+1 in flight, so vmcnt(TL) would be a
// no-op there -- must drain vmcnt(0) (epilogue ledger rule; R6 race).
// LDS layout per slot: [A: BM rows][B: BN rows] x 8 chunks of 16B; chunk c of
// row r holds global chunk c^(r&7) (T2 involution swizzle).
// EPI 0: bf16 out, *scale      1: f32 out + res     2: +bias, GELU, bf16
// EPI 3: +bias +res, f32       4: bf16 out TRANSPOSED per-head (V^T producer)
template<int EPI, int BM, int BN, int WVM, int WVN>
__global__ __launch_bounds__(WVM * WVN * 64, 2) void gemm_pipe(
    const unsigned short* __restrict__ A, const unsigned short* __restrict__ BT,
    void* __restrict__ Cp, const float* __restrict__ bias,
    const float* __restrict__ res, int Nsz, int Ksz, float scale)
{
    constexpr int NT = WVM * WVN * 64;         // threads
    constexpr int TOTCH = (BM + BN) * 8;       // 16B chunks per tile (A|B)
    constexpr int TL = TOTCH / NT;             // gload_lds per thread per tile
    constexpr int MREP = BM / (WVM * 16);
    constexpr int WMR = MREP * 16;             // wave rows
    __shared__ alignas(16) unsigned short lds[2][(BM + BN) * 64];

    const int t = threadIdx.x, l = t & 63, w = t >> 6;
    const int wm = w / WVN, wn = w % WVN;
    const int lr = l & 15, lg = l >> 4;
    const int bm = blockIdx.x, bn = blockIdx.y;

    f32x4 acc[MREP][4] = {};

    const int nk = Ksz / 64;

    auto STAGE = [&](int tile, char* slot) {
        const int k0 = tile * 64;
        #pragma unroll
        for (int p = 0; p < TL; ++p) {
            const int ci = t + p * NT;
            const bool isA = ci < BM * 8;
            const int rr = (isA ? ci : ci - BM * 8) >> 3;
            const int cc = ci & 7;
            const unsigned short* srow = isA
                ? A + (size_t)(bm * BM + rr) * Ksz
                : BT + (size_t)(bn * BN + rr) * Ksz;
            gload16(srow + k0 + ((cc ^ (rr & 7)) << 3), slot + ci * 16);
        }
    };

    STAGE(0, (char*)lds[0]);
    STAGE(1, (char*)lds[1]);

    for (int kt = 0; kt < nk; ++kt) {
        char* slot = (char*)lds[kt & 1];
        const char* la = slot;
        const char* lb = slot + BM * 128;
        if (kt + 1 < nk) {  // tile kt+1 still in flight: counted wait
            if constexpr (TL == 8) asm volatile("s_waitcnt vmcnt(8)" ::: "memory");
            else                   asm volatile("s_waitcnt vmcnt(6)" ::: "memory");
        } else {            // last tile: nothing behind it -- full drain
            asm volatile("s_waitcnt vmcnt(0)" ::: "memory");
        }
        __builtin_amdgcn_s_barrier();
        __builtin_amdgcn_sched_barrier(0);

        __builtin_amdgcn_s_setprio(1);
        #pragma unroll
        for (int ks = 0; ks < 2; ++ks) {
            bf16x8 af[MREP], bfr[4];
            #pragma unroll
            for (int i = 0; i < MREP; ++i) {
                const int ra = wm * WMR + i * 16 + lr;
                af[i] = *(const bf16x8*)(la + (ra * 8 + ((ks * 4 + lg) ^ (ra & 7))) * 16);
            }
            #pragma unroll
            for (int i = 0; i < 4; ++i) {
                const int rb_ = wn * 64 + i * 16 + lr;
                bfr[i] = *(const bf16x8*)(lb + (rb_ * 8 + ((ks * 4 + lg) ^ (rb_ & 7))) * 16);
            }
            #pragma unroll
            for (int mb = 0; mb < MREP; ++mb)
                #pragma unroll
                for (int nb = 0; nb < 4; ++nb) {
                    if (EPI == 4)  // swapped operands -> transposed output tile
                        acc[mb][nb] = __builtin_amdgcn_mfma_f32_16x16x32_bf16(
                            bfr[nb], af[mb], acc[mb][nb], 0, 0, 0);
                    else
                        acc[mb][nb] = __builtin_amdgcn_mfma_f32_16x16x32_bf16(
                            af[mb], bfr[nb], acc[mb][nb], 0, 0, 0);
                }
        }
        __builtin_amdgcn_s_setprio(0);
        __builtin_amdgcn_s_barrier();
        if (kt + 2 < nk) STAGE(kt + 2, slot);
    }

    const int rb = bm * BM + wm * WMR, cb = bn * BN + wn * 64;
    #pragma unroll
    for (int mb = 0; mb < MREP; ++mb)
        #pragma unroll
        for (int nb = 0; nb < 4; ++nb)
            #pragma unroll
            for (int r = 0; r < 4; ++r) {
                float v = acc[mb][nb][r];
                if (EPI == 4) {
                    const int xrow = rb + mb * 16 + lr;          // token row
                    const int feat = cb + nb * 16 + lg * 4 + r;  // output feature
                    const int bb = xrow >> 11, s = xrow & (SEQ - 1);
                    ((unsigned short*)Cp)[((size_t)bb * DM + feat) * SEQ + s] = f2bf_bits(v);
                    continue;
                }
                const int row = rb + mb * 16 + lg * 4 + r;
                const int col = cb + nb * 16 + lr;
                const size_t idx = (size_t)row * Nsz + col;
                if (EPI == 0) {
                    ((unsigned short*)Cp)[idx] = f2bf_bits(v * scale);
                } else if (EPI == 1) {
                    ((float*)Cp)[idx] = v + res[idx];
                } else if (EPI == 2) {
                    float xx = v + bias[col];
                    ((unsigned short*)Cp)[idx] =
                        f2bf_bits(0.5f * xx * (1.0f + erff(xx * 0.70710678118654752f)));
                } else {
                    ((float*)Cp)[idx] = v + bias[col] + res[idx];
                }
            }
}

// ---------------- causal flash attention (double-buffered, KVB=128) --------
// QKg: [B][S][2048] bf16 (Q | K fused, Q pre-scaled 1/8), head h at cols h*64 / 1024+h*64.
// VTg: [B][DM][S] bf16 (V transposed per head).
// Og:  [B][S][DM] bf16.
// grid (16 qtiles, 32 bh), block 512 (8 waves, 16 q-rows each; QBLK=128, KVB=128).
// Tiles staged swizzled: lds 16B-chunk c of row r holds global chunk c^(r&mask).
__global__ __launch_bounds__(512, 4) void attn_kernel(
    const unsigned short* __restrict__ QKg, const unsigned short* __restrict__ VTg,
    unsigned short* __restrict__ Og)
{
    __shared__ alignas(16) unsigned short ldsK[2][128 * 64];
    __shared__ alignas(16) unsigned short ldsVT[2][64 * 128];
    const int t = threadIdx.x, l = t & 63, w = t >> 6;
    const int lr = l & 15, lg = l >> 4;
    const int qt = (int)gridDim.x - 1 - blockIdx.x;  // longest blocks first
    const int bh = blockIdx.y;
    const int b = bh >> 4, h = bh & 15;
    const unsigned short* Qbase = QKg + (size_t)b * SEQ * 2048 + h * 64;
    const unsigned short* Kbase = Qbase + 1024;
    const unsigned short* Vbase = VTg + (size_t)b * DM * SEQ + (size_t)(h * 64) * SEQ;

    const int wq0 = qt * 128 + w * 16;   // wave's first q row
    const int qrow = wq0 + lr;           // this lane's q row
    bf16x8 qf[2];
    #pragma unroll
    for (int ks = 0; ks < 2; ++ks)
        qf[ks] = *(const bf16x8*)(Qbase + (size_t)qrow * 2048 + ks * 32 + lg * 8);

    float m_run = -1e30f, l_run = 0.0f;
    f32x4 oacc[4] = {};

    // staging: per thread 2 chunks of K (128x64) and 2 of VT (64x128)
    const int kci[2] = { t, t + 512 };

    const int nkt = qt + 1;

    // prologue: stage tile 0 into buf 0
    #pragma unroll
    for (int p = 0; p < 2; ++p) {
        const int ci = kci[p];
        const int kr = ci >> 3, kc = (ci & 7) ^ (kr & 7);
        gload16(Kbase + (size_t)kr * 2048 + kc * 8, (char*)ldsK[0] + ci * 16);
        const int vr = ci >> 4, vc = (ci & 15) ^ (vr & 15);
        gload16(Vbase + (size_t)vr * SEQ + vc * 8, (char*)ldsVT[0] + ci * 16);
    }
    asm volatile("s_waitcnt vmcnt(0)" ::: "memory");
    __builtin_amdgcn_s_barrier();

    for (int kt = 0; kt < nkt; ++kt) {
        const int cur = kt & 1;
        // issue next-tile staging into the other buffer (safe: separated from
        // its readers by the barrier at the end of the previous iteration)
        if (kt + 1 < nkt) {
            #pragma unroll
            for (int p = 0; p < 2; ++p) {
                const int ci = kci[p];
                const int kr = ci >> 3, kc = (ci & 7) ^ (kr & 7);
                gload16(Kbase + (size_t)((kt + 1) * 128 + kr) * 2048 + kc * 8,
                        (char*)ldsK[cur ^ 1] + ci * 16);
                const int vr = ci >> 4, vc = (ci & 15) ^ (vr & 15);
                gload16(Vbase + (size_t)vr * SEQ + (kt + 1) * 128 + vc * 8,
                        (char*)ldsVT[cur ^ 1] + ci * 16);
            }
        }
        const char* lk = (const char*)ldsK[cur];
        const char* lv = (const char*)ldsVT[cur];

        // S^T = K . Q^T : lane holds q = lr, key = mb*16 + lg*4 + reg
        __builtin_amdgcn_s_setprio(1);
        f32x4 st[8] = {};
        #pragma unroll
        for (int ks = 0; ks < 2; ++ks)
            #pragma unroll
            for (int mb = 0; mb < 8; ++mb) {
                bf16x8 kf = *(const bf16x8*)(lk + (mb * 16 + lr) * 128
                                             + (((ks * 4 + lg) ^ (lr & 7)) * 16));
                st[mb] = __builtin_amdgcn_mfma_f32_16x16x32_bf16(kf, qf[ks], st[mb], 0, 0, 0);
            }
        __builtin_amdgcn_s_setprio(0);

        const int kt0 = kt * 128;
        if (kt0 + 127 > wq0) {  // wave-uniform: diagonal tile
            #pragma unroll
            for (int mb = 0; mb < 8; ++mb)
                #pragma unroll
                for (int r = 0; r < 4; ++r)
                    if (kt0 + mb * 16 + lg * 4 + r > qrow) st[mb][r] = -1e30f;
        }

        float mt = -1e30f;
        #pragma unroll
        for (int mb = 0; mb < 8; ++mb)
            mt = fmaxf(mt, fmaxf(fmaxf(st[mb][0], st[mb][1]), fmaxf(st[mb][2], st[mb][3])));
        mt = fmaxf(mt, __shfl_xor(mt, 16));
        mt = fmaxf(mt, __shfl_xor(mt, 32));

        // defer-max (T13): only rescale when tile max exceeds running max + 8
        if (!__all(mt <= m_run + 8.0f)) {
            const float m_new = fmaxf(m_run, mt);
            const float alpha = exp2f((m_run - m_new) * LOG2E);
            l_run *= alpha;
            #pragma unroll
            for (int j = 0; j < 4; ++j) {
                const float aj = __shfl(alpha, lg * 4 + j);
                #pragma unroll
                for (int nb = 0; nb < 4; ++nb) oacc[nb][j] *= aj;
            }
            m_run = m_new;
        }

        const float nml = m_run * LOG2E;
        float rs = 0.0f;
        #pragma unroll
        for (int mb = 0; mb < 8; ++mb)
            #pragma unroll
            for (int r = 0; r < 4; ++r) {
                const float p = exp2f(fmaf(st[mb][r], LOG2E, -nml));
                st[mb][r] = p;
                rs += p;
            }
        rs += __shfl_xor(rs, 16);
        rs += __shfl_xor(rs, 32);
        l_run += rs;

        // P -> A-frags in-register. Slot map f(lg,j) = 16*(j>>2) + lg*4 + (j&3),
        // keys = 32*ks + f.
        bf16x8 pa[4];
        #pragma unroll
        for (int ks = 0; ks < 4; ++ks)
            #pragma unroll
            for (int j = 0; j < 4; ++j) {
                pa[ks][j]     = (__bf16)st[2 * ks][j];
                pa[ks][j + 4] = (__bf16)st[2 * ks + 1][j];
            }

        // V B-frags from swizzled VT rows: slot j holds V[32ks+f(lg,j)][n=16nb+lr]
        __builtin_amdgcn_s_setprio(1);
        #pragma unroll
        for (int ks = 0; ks < 4; ++ks)
            #pragma unroll
            for (int nb = 0; nb < 4; ++nb) {
                const int n = nb * 16 + lr;
                union { bf16x8 v; uint64_t d[2]; } vb;
                vb.d[0] = *(const uint64_t*)(lv + n * 256
                            + (((4 * ks + (lg >> 1)) ^ (n & 15)) * 16) + 8 * (lg & 1));
                vb.d[1] = *(const uint64_t*)(lv + n * 256
                            + (((4 * ks + 2 + (lg >> 1)) ^ (n & 15)) * 16) + 8 * (lg & 1));
                oacc[nb] = __builtin_amdgcn_mfma_f32_16x16x32_bf16(pa[ks], vb.v, oacc[nb], 0, 0, 0);
            }
        __builtin_amdgcn_s_setprio(0);

        // single drain + barrier per tile: next tile's loads are now complete
        asm volatile("s_waitcnt vmcnt(0)" ::: "memory");
        __builtin_amdgcn_s_barrier();
    }

    unsigned short* Ob = Og + (size_t)b * SEQ * DM + h * 64;
    #pragma unroll
    for (int j = 0; j < 4; ++j) {
        const float inv = 1.0f / __shfl(l_run, lg * 4 + j);
        const int row = wq0 + lg * 4 + j;
        #pragma unroll
        for (int nb = 0; nb < 4; ++nb)
            Ob[(size_t)row * DM + nb * 16 + lr] = f2bf_bits(oacc[nb][j] * inv);
    }
}

// ---------------- launcher ----------------
extern "C" void kernel_launch(void* const* d_in, const int* in_sizes, int n_in,
                              void* d_out, int out_size, void* d_ws, size_t ws_size,
                              hipStream_t stream) {
    (void)in_sizes; (void)n_in; (void)out_size; (void)ws_size;
    const float* x    = (const float*)d_in[0];
    const float* Wq   = (const float*)d_in[1];
    const float* Wk   = (const float*)d_in[2];
    const float* Wv   = (const float*)d_in[3];
    const float* Wo   = (const float*)d_in[4];
    const float* ln1g = (const float*)d_in[5];
    const float* ln1b = (const float*)d_in[6];
    const float* ln2g = (const float*)d_in[7];
    const float* ln2b = (const float*)d_in[8];
    const float* W1   = (const float*)d_in[9];
    const float* b1   = (const float*)d_in[10];
    const float* W2   = (const float*)d_in[11];
    const float* b2   = (const float*)d_in[12];
    float* out = (float*)d_out;

    char* ws = (char*)d_ws;
    const size_t MB = 1ull << 20;
    unsigned short* xn1   = (unsigned short*)(ws + 0 * MB);   // 8 MB [4096][1024]
    unsigned short* QKb   = (unsigned short*)(ws + 8 * MB);   // 16 MB [2][2048][2048]
    unsigned short* VTg   = (unsigned short*)(ws + 24 * MB);  // 8 MB [2][1024][2048]
    unsigned short* ffa   = (unsigned short*)(ws + 0 * MB);   // 32 MB (aliases xn1/QKb/VTg)
    unsigned short* attno = (unsigned short*)(ws + 32 * MB);  // 8 MB
    float*          x2    = (float*)(ws + 40 * MB);           // 16 MB
    unsigned short* h2    = (unsigned short*)(ws + 56 * MB);  // 8 MB
    unsigned short* WqkT  = (unsigned short*)(ws + 64 * MB);  // 4 MB [2048][1024]
    unsigned short* WvT   = (unsigned short*)(ws + 68 * MB);  // 2 MB
    unsigned short* WoT   = (unsigned short*)(ws + 70 * MB);  // 2 MB
    unsigned short* W1T   = (unsigned short*)(ws + 72 * MB);  // 8 MB
    unsigned short* W2T   = (unsigned short*)(ws + 80 * MB);  // 8 MB  (total 88 MB)

    dim3 blk(256);
    wtrans_kernel<<<dim3(16, 16), blk, 0, stream>>>(Wq, WqkT, DM, DM, 0.125f);
    wtrans_kernel<<<dim3(16, 16), blk, 0, stream>>>(Wk, WqkT + DM * DM, DM, DM, 1.0f);
    wtrans_kernel<<<dim3(16, 16), blk, 0, stream>>>(Wv, WvT, DM, DM, 1.0f);
    wtrans_kernel<<<dim3(16, 16), blk, 0, stream>>>(Wo, WoT, DM, DM, 1.0f);
    wtrans_kernel<<<dim3(16, 64), blk, 0, stream>>>(W1, W1T, DM, DFF, 1.0f);
    wtrans_kernel<<<dim3(64, 16), blk, 0, stream>>>(W2, W2T, DFF, DM, 1.0f);

    ln_kernel<<<dim3(MT), blk, 0, stream>>>(x, ln1g, ln1b, xn1);

    // fused Q|K projection (N=2048) and transposed V projection
    gemm_pipe<0, 128, 256, 2, 4><<<dim3(32, 8), dim3(512), 0, stream>>>(
        xn1, WqkT, QKb, nullptr, nullptr, 2048, DM, 1.0f);
    gemm_pipe<4, 128, 128, 2, 2><<<dim3(32, 8), dim3(256), 0, stream>>>(
        xn1, WvT, VTg, nullptr, nullptr, DM, DM, 1.0f);

    attn_kernel<<<dim3(16, 32), dim3(512), 0, stream>>>(QKb, VTg, attno);

    gemm_pipe<1, 128, 128, 2, 2><<<dim3(32, 8), dim3(256), 0, stream>>>(
        attno, WoT, x2, nullptr, x, DM, DM, 1.0f);

    ln_kernel<<<dim3(MT), blk, 0, stream>>>(x2, ln2g, ln2b, h2);

    gemm_pipe<2, 256, 256, 2, 4><<<dim3(16, 16), dim3(512), 0, stream>>>(
        h2, W1T, ffa, b1, nullptr, DFF, DM, 1.0f);
    gemm_pipe<3, 128, 128, 2, 2><<<dim3(32, 8), dim3(256), 0, stream>>>(
        ffa, W2T, out, b2, x2, DM, DFF, 1.0f);
}

// Round 8
// 239.891 us; speedup vs baseline: 1.5613x; 1.0821x over previous
//
#include <hip/hip_runtime.h>
#include <cstdint>
#include <cstddef>

#define DEV __device__ __forceinline__

typedef __attribute__((ext_vector_type(8))) __bf16 bf16x8;
typedef __attribute__((ext_vector_type(4))) float f32x4;
typedef __attribute__((ext_vector_type(8))) unsigned short u16x8;

typedef const __attribute__((address_space(1))) void gld_gv;
typedef __attribute__((address_space(3))) void gld_sv;

static constexpr int SEQ = 2048, BAT = 2, DM = 1024, DFF = 4096;
static constexpr int MT = BAT * SEQ;  // 4096 rows total
static constexpr float LOG2E = 1.44269504088896340736f;

DEV unsigned short f2bf_bits(float f) {
    uint32_t u = __builtin_bit_cast(uint32_t, f);
    return (unsigned short)((u + 0x7FFFu + ((u >> 16) & 1u)) >> 16);
}

DEV void gload16(const void* g, void* s) {
    __builtin_amdgcn_global_load_lds((gld_gv*)g, (gld_sv*)s, 16, 0, 0);
}

// ---------------- weight transpose + fp32->bf16 convert (+scale) -----------
__global__ __launch_bounds__(256) void wtrans_kernel(const float* __restrict__ W,
        unsigned short* __restrict__ WT, int K, int N, float scale)
{
    __shared__ float tile[64][65];
    const int k0 = blockIdx.x * 64, n0 = blockIdx.y * 64;
    const int t = threadIdx.x, r = t >> 6, c = t & 63;
    #pragma unroll
    for (int p = 0; p < 16; ++p)
        tile[p * 4 + r][c] = W[(size_t)(k0 + p * 4 + r) * N + n0 + c];
    __syncthreads();
    #pragma unroll
    for (int p = 0; p < 16; ++p)
        WT[(size_t)(n0 + p * 4 + r) * K + k0 + c] = f2bf_bits(tile[c][p * 4 + r] * scale);
}

// ---------------- LayerNorm (f32 in -> bf16 out) ----------------
__global__ __launch_bounds__(256) void ln_kernel(const float* __restrict__ x,
        const float* __restrict__ gw, const float* __restrict__ bw,
        unsigned short* __restrict__ y)
{
    const int row = blockIdx.x, t = threadIdx.x;
    const float* xr = x + (size_t)row * DM;
    float4 v = *(const float4*)(xr + t * 4);
    float s = v.x + v.y + v.z + v.w;
    float q = v.x * v.x + v.y * v.y + v.z * v.z + v.w * v.w;
    #pragma unroll
    for (int m = 1; m < 64; m <<= 1) { s += __shfl_xor(s, m); q += __shfl_xor(q, m); }
    __shared__ float red[8];
    const int w = t >> 6;
    if ((t & 63) == 0) { red[w] = s; red[4 + w] = q; }
    __syncthreads();
    s = red[0] + red[1] + red[2] + red[3];
    q = red[4] + red[5] + red[6] + red[7];
    const float mu = s * (1.0f / DM);
    const float rstd = rsqrtf(q * (1.0f / DM) - mu * mu + 1e-5f);
    float4 g4 = *(const float4*)(gw + t * 4);
    float4 b4 = *(const float4*)(bw + t * 4);
    short4 o;
    o.x = (short)f2bf_bits((v.x - mu) * rstd * g4.x + b4.x);
    o.y = (short)f2bf_bits((v.y - mu) * rstd * g4.y + b4.y);
    o.z = (short)f2bf_bits((v.z - mu) * rstd * g4.z + b4.z);
    o.w = (short)f2bf_bits((v.w - mu) * rstd * g4.w + b4.w);
    *(short4*)(y + (size_t)row * DM + t * 4) = o;
}

// ---------------- GEMM: depth-2 pipelined, counted vmcnt, swizzled LDS -----
// (unchanged from R7; see comments there)
template<int EPI, int BM, int BN, int WVM, int WVN>
__global__ __launch_bounds__(WVM * WVN * 64, 2) void gemm_pipe(
    const unsigned short* __restrict__ A, const unsigned short* __restrict__ BT,
    void* __restrict__ Cp, const float* __restrict__ bias,
    const float* __restrict__ res, int Nsz, int Ksz, float scale)
{
    constexpr int NT = WVM * WVN * 64;         // threads
    constexpr int TOTCH = (BM + BN) * 8;       // 16B chunks per tile (A|B)
    constexpr int TL = TOTCH / NT;             // gload_lds per thread per tile
    constexpr int MREP = BM / (WVM * 16);
    constexpr int WMR = MREP * 16;             // wave rows
    __shared__ alignas(16) unsigned short lds[2][(BM + BN) * 64];

    const int t = threadIdx.x, l = t & 63, w = t >> 6;
    const int wm = w / WVN, wn = w % WVN;
    const int lr = l & 15, lg = l >> 4;
    const int bm = blockIdx.x, bn = blockIdx.y;

    f32x4 acc[MREP][4] = {};

    const int nk = Ksz / 64;

    auto STAGE = [&](int tile, char* slot) {
        const int k0 = tile * 64;
        #pragma unroll
        for (int p = 0; p < TL; ++p) {
            const int ci = t + p * NT;
            const bool isA = ci < BM * 8;
            const int rr = (isA ? ci : ci - BM * 8) >> 3;
            const int cc = ci & 7;
            const unsigned short* srow = isA
                ? A + (size_t)(bm * BM + rr) * Ksz
                : BT + (size_t)(bn * BN + rr) * Ksz;
            gload16(srow + k0 + ((cc ^ (rr & 7)) << 3), slot + ci * 16);
        }
    };

    STAGE(0, (char*)lds[0]);
    STAGE(1, (char*)lds[1]);

    for (int kt = 0; kt < nk; ++kt) {
        char* slot = (char*)lds[kt & 1];
        const char* la = slot;
        const char* lb = slot + BM * 128;
        if (kt + 1 < nk) {  // tile kt+1 still in flight: counted wait
            if constexpr (TL == 8) asm volatile("s_waitcnt vmcnt(8)" ::: "memory");
            else                   asm volatile("s_waitcnt vmcnt(6)" ::: "memory");
        } else {            // last tile: nothing behind it -- full drain
            asm volatile("s_waitcnt vmcnt(0)" ::: "memory");
        }
        __builtin_amdgcn_s_barrier();
        __builtin_amdgcn_sched_barrier(0);

        __builtin_amdgcn_s_setprio(1);
        #pragma unroll
        for (int ks = 0; ks < 2; ++ks) {
            bf16x8 af[MREP], bfr[4];
            #pragma unroll
            for (int i = 0; i < MREP; ++i) {
                const int ra = wm * WMR + i * 16 + lr;
                af[i] = *(const bf16x8*)(la + (ra * 8 + ((ks * 4 + lg) ^ (ra & 7))) * 16);
            }
            #pragma unroll
            for (int i = 0; i < 4; ++i) {
                const int rb_ = wn * 64 + i * 16 + lr;
                bfr[i] = *(const bf16x8*)(lb + (rb_ * 8 + ((ks * 4 + lg) ^ (rb_ & 7))) * 16);
            }
            #pragma unroll
            for (int mb = 0; mb < MREP; ++mb)
                #pragma unroll
                for (int nb = 0; nb < 4; ++nb) {
                    if (EPI == 4)  // swapped operands -> transposed output tile
                        acc[mb][nb] = __builtin_amdgcn_mfma_f32_16x16x32_bf16(
                            bfr[nb], af[mb], acc[mb][nb], 0, 0, 0);
                    else
                        acc[mb][nb] = __builtin_amdgcn_mfma_f32_16x16x32_bf16(
                            af[mb], bfr[nb], acc[mb][nb], 0, 0, 0);
                }
        }
        __builtin_amdgcn_s_setprio(0);
        __builtin_amdgcn_s_barrier();
        if (kt + 2 < nk) STAGE(kt + 2, slot);
    }

    const int rb = bm * BM + wm * WMR, cb = bn * BN + wn * 64;
    #pragma unroll
    for (int mb = 0; mb < MREP; ++mb)
        #pragma unroll
        for (int nb = 0; nb < 4; ++nb)
            #pragma unroll
            for (int r = 0; r < 4; ++r) {
                float v = acc[mb][nb][r];
                if (EPI == 4) {
                    const int xrow = rb + mb * 16 + lr;          // token row
                    const int feat = cb + nb * 16 + lg * 4 + r;  // output feature
                    const int bb = xrow >> 11, s = xrow & (SEQ - 1);
                    ((unsigned short*)Cp)[((size_t)bb * DM + feat) * SEQ + s] = f2bf_bits(v);
                    continue;
                }
                const int row = rb + mb * 16 + lg * 4 + r;
                const int col = cb + nb * 16 + lr;
                const size_t idx = (size_t)row * Nsz + col;
                if (EPI == 0) {
                    ((unsigned short*)Cp)[idx] = f2bf_bits(v * scale);
                } else if (EPI == 1) {
                    ((float*)Cp)[idx] = v + res[idx];
                } else if (EPI == 2) {
                    float xx = v + bias[col];
                    ((unsigned short*)Cp)[idx] =
                        f2bf_bits(0.5f * xx * (1.0f + erff(xx * 0.70710678118654752f)));
                } else {
                    ((float*)Cp)[idx] = v + bias[col] + res[idx];
                }
            }
}

// ---------------- causal flash attention (mirrored q-tile pairing) ---------
// QKg: [B][S][2048] bf16 (Q | K fused, Q pre-scaled 1/8), head h at cols h*64 / 1024+h*64.
// VTg: [B][DM][S] bf16 (V transposed per head).  Og: [B][S][DM] bf16.
// grid (8, 32 bh), block 512 (8 waves). Block x handles q-tiles qtA=x and
// qtB=15-x (QBLK=128 each), sharing the K/V stream: loop kt=0..qtB, tile A
// active while kt<=qtA -> every block does exactly 17 tile-computes (uniform
// work, 1 block/CU), and K/V staging is shared between the two tiles.
// Softmax: lane-local defer-max check (cross-lane reduce only when triggered),
// per-lane partial l (reduced once at the end). Tiles staged swizzled.
__global__ __launch_bounds__(512, 2) void attn_kernel(
    const unsigned short* __restrict__ QKg, const unsigned short* __restrict__ VTg,
    unsigned short* __restrict__ Og)
{
    __shared__ alignas(16) unsigned short ldsK[2][128 * 64];
    __shared__ alignas(16) unsigned short ldsVT[2][64 * 128];
    const int t = threadIdx.x, l = t & 63, w = t >> 6;
    const int lr = l & 15, lg = l >> 4;
    const int qtA = blockIdx.x, qtB = 15 - qtA;
    const int bh = blockIdx.y;
    const int b = bh >> 4, h = bh & 15;
    const unsigned short* Qbase = QKg + (size_t)b * SEQ * 2048 + h * 64;
    const unsigned short* Kbase = Qbase + 1024;
    const unsigned short* Vbase = VTg + (size_t)b * DM * SEQ + (size_t)(h * 64) * SEQ;

    const int wq0A = qtA * 128 + w * 16, qrowA = wq0A + lr;
    const int wq0B = qtB * 128 + w * 16, qrowB = wq0B + lr;
    bf16x8 qfA[2], qfB[2];
    #pragma unroll
    for (int ks = 0; ks < 2; ++ks) {
        qfA[ks] = *(const bf16x8*)(Qbase + (size_t)qrowA * 2048 + ks * 32 + lg * 8);
        qfB[ks] = *(const bf16x8*)(Qbase + (size_t)qrowB * 2048 + ks * 32 + lg * 8);
    }

    float m_runA = -1e30f, l_partA = 0.0f;
    float m_runB = -1e30f, l_partB = 0.0f;
    f32x4 oaccA[4] = {}, oaccB[4] = {};

    const int kci[2] = { t, t + 512 };
    const int nkt = qtB + 1;

    // prologue: stage tile 0 into buf 0
    #pragma unroll
    for (int p = 0; p < 2; ++p) {
        const int ci = kci[p];
        const int kr = ci >> 3, kc = (ci & 7) ^ (kr & 7);
        gload16(Kbase + (size_t)kr * 2048 + kc * 8, (char*)ldsK[0] + ci * 16);
        const int vr = ci >> 4, vc = (ci & 15) ^ (vr & 15);
        gload16(Vbase + (size_t)vr * SEQ + vc * 8, (char*)ldsVT[0] + ci * 16);
    }
    asm volatile("s_waitcnt vmcnt(0)" ::: "memory");
    __builtin_amdgcn_s_barrier();

    for (int kt = 0; kt < nkt; ++kt) {
        const int cur = kt & 1;
        if (kt + 1 < nkt) {
            #pragma unroll
            for (int p = 0; p < 2; ++p) {
                const int ci = kci[p];
                const int kr = ci >> 3, kc = (ci & 7) ^ (kr & 7);
                gload16(Kbase + (size_t)((kt + 1) * 128 + kr) * 2048 + kc * 8,
                        (char*)ldsK[cur ^ 1] + ci * 16);
                const int vr = ci >> 4, vc = (ci & 15) ^ (vr & 15);
                gload16(Vbase + (size_t)vr * SEQ + (kt + 1) * 128 + vc * 8,
                        (char*)ldsVT[cur ^ 1] + ci * 16);
            }
        }
        const char* lk = (const char*)ldsK[cur];
        const char* lv = (const char*)ldsVT[cur];

        // one q-tile against the current K/V tile
        auto process = [&](const bf16x8 (&qf)[2], f32x4 (&oacc)[4],
                           float& m_run, float& l_part, int qrow, bool diag) {
            // S^T = K . Q^T : lane holds q = lr, key = mb*16 + lg*4 + reg
            __builtin_amdgcn_s_setprio(1);
            f32x4 st[8] = {};
            #pragma unroll
            for (int ks = 0; ks < 2; ++ks)
                #pragma unroll
                for (int mb = 0; mb < 8; ++mb) {
                    bf16x8 kf = *(const bf16x8*)(lk + (mb * 16 + lr) * 128
                                                 + (((ks * 4 + lg) ^ (lr & 7)) * 16));
                    st[mb] = __builtin_amdgcn_mfma_f32_16x16x32_bf16(kf, qf[ks], st[mb], 0, 0, 0);
                }
            __builtin_amdgcn_s_setprio(0);

            const int kt0 = kt * 128;
            if (diag) {
                #pragma unroll
                for (int mb = 0; mb < 8; ++mb)
                    #pragma unroll
                    for (int r = 0; r < 4; ++r)
                        if (kt0 + mb * 16 + lg * 4 + r > qrow) st[mb][r] = -1e30f;
            }

            // lane-local max (tree)
            f32x4 mx4 = st[0];
            #pragma unroll
            for (int mb = 1; mb < 8; ++mb) {
                mx4[0] = fmaxf(mx4[0], st[mb][0]); mx4[1] = fmaxf(mx4[1], st[mb][1]);
                mx4[2] = fmaxf(mx4[2], st[mb][2]); mx4[3] = fmaxf(mx4[3], st[mb][3]);
            }
            const float mt = fmaxf(fmaxf(mx4[0], mx4[1]), fmaxf(mx4[2], mx4[3]));

            // defer-max (T13) with LANE-LOCAL check: reduce only when triggered
            if (!__all(mt <= m_run + 8.0f)) {
                float mr = fmaxf(mt, __shfl_xor(mt, 16));
                mr = fmaxf(mr, __shfl_xor(mr, 32));
                const float m_new = fmaxf(m_run, mr);
                const float alpha = exp2f((m_run - m_new) * LOG2E);
                l_part *= alpha;
                #pragma unroll
                for (int j = 0; j < 4; ++j) {
                    const float aj = __shfl(alpha, lg * 4 + j);
                    #pragma unroll
                    for (int nb = 0; nb < 4; ++nb) oacc[nb][j] *= aj;
                }
                m_run = m_new;
            }

            const float nml = m_run * LOG2E;
            float rsl = 0.0f;
            #pragma unroll
            for (int mb = 0; mb < 8; ++mb)
                #pragma unroll
                for (int r = 0; r < 4; ++r) {
                    const float p = exp2f(fmaf(st[mb][r], LOG2E, -nml));
                    st[mb][r] = p;
                    rsl += p;
                }
            l_part += rsl;   // per-lane partial; reduced once at the end

            // P -> A-frags. Slot map f(lg,j) = 16*(j>>2) + lg*4 + (j&3), keys = 32ks + f.
            bf16x8 pa[4];
            #pragma unroll
            for (int ks = 0; ks < 4; ++ks)
                #pragma unroll
                for (int j = 0; j < 4; ++j) {
                    pa[ks][j]     = (__bf16)st[2 * ks][j];
                    pa[ks][j + 4] = (__bf16)st[2 * ks + 1][j];
                }

            // V B-frags from swizzled VT rows: slot j holds V[32ks+f(lg,j)][n=16nb+lr]
            __builtin_amdgcn_s_setprio(1);
            #pragma unroll
            for (int ks = 0; ks < 4; ++ks)
                #pragma unroll
                for (int nb = 0; nb < 4; ++nb) {
                    const int n = nb * 16 + lr;
                    union { bf16x8 v; uint64_t d[2]; } vb;
                    vb.d[0] = *(const uint64_t*)(lv + n * 256
                                + (((4 * ks + (lg >> 1)) ^ (n & 15)) * 16) + 8 * (lg & 1));
                    vb.d[1] = *(const uint64_t*)(lv + n * 256
                                + (((4 * ks + 2 + (lg >> 1)) ^ (n & 15)) * 16) + 8 * (lg & 1));
                    oacc[nb] = __builtin_amdgcn_mfma_f32_16x16x32_bf16(pa[ks], vb.v, oacc[nb], 0, 0, 0);
                }
            __builtin_amdgcn_s_setprio(0);
        };

        if (kt <= qtA) process(qfA, oaccA, m_runA, l_partA, qrowA, kt == qtA);
        process(qfB, oaccB, m_runB, l_partB, qrowB, kt == qtB);

        // single drain + barrier per tile: next tile's loads are now complete
        asm volatile("s_waitcnt vmcnt(0)" ::: "memory");
        __builtin_amdgcn_s_barrier();
    }

    unsigned short* Obase = Og + (size_t)b * SEQ * DM + h * 64;
    {
        float lr_ = l_partA;
        lr_ += __shfl_xor(lr_, 16); lr_ += __shfl_xor(lr_, 32);
        #pragma unroll
        for (int j = 0; j < 4; ++j) {
            const float inv = 1.0f / __shfl(lr_, lg * 4 + j);
            const int row = wq0A + lg * 4 + j;
            #pragma unroll
            for (int nb = 0; nb < 4; ++nb)
                Obase[(size_t)row * DM + nb * 16 + lr] = f2bf_bits(oaccA[nb][j] * inv);
        }
    }
    {
        float lr_ = l_partB;
        lr_ += __shfl_xor(lr_, 16); lr_ += __shfl_xor(lr_, 32);
        #pragma unroll
        for (int j = 0; j < 4; ++j) {
            const float inv = 1.0f / __shfl(lr_, lg * 4 + j);
            const int row = wq0B + lg * 4 + j;
            #pragma unroll
            for (int nb = 0; nb < 4; ++nb)
                Obase[(size_t)row * DM + nb * 16 + lr] = f2bf_bits(oaccB[nb][j] * inv);
        }
    }
}

// ---------------- launcher ----------------
extern "C" void kernel_launch(void* const* d_in, const int* in_sizes, int n_in,
                              void* d_out, int out_size, void* d_ws, size_t ws_size,
                              hipStream_t stream) {
    (void)in_sizes; (void)n_in; (void)out_size; (void)ws_size;
    const float* x    = (const float*)d_in[0];
    const float* Wq   = (const float*)d_in[1];
    const float* Wk   = (const float*)d_in[2];
    const float* Wv   = (const float*)d_in[3];
    const float* Wo   = (const float*)d_in[4];
    const float* ln1g = (const float*)d_in[5];
    const float* ln1b = (const float*)d_in[6];
    const float* ln2g = (const float*)d_in[7];
    const float* ln2b = (const float*)d_in[8];
    const float* W1   = (const float*)d_in[9];
    const float* b1   = (const float*)d_in[10];
    const float* W2   = (const float*)d_in[11];
    const float* b2   = (const float*)d_in[12];
    float* out = (float*)d_out;

    char* ws = (char*)d_ws;
    const size_t MB = 1ull << 20;
    unsigned short* xn1   = (unsigned short*)(ws + 0 * MB);   // 8 MB [4096][1024]
    unsigned short* QKb   = (unsigned short*)(ws + 8 * MB);   // 16 MB [2][2048][2048]
    unsigned short* VTg   = (unsigned short*)(ws + 24 * MB);  // 8 MB [2][1024][2048]
    unsigned short* ffa   = (unsigned short*)(ws + 0 * MB);   // 32 MB (aliases xn1/QKb/VTg)
    unsigned short* attno = (unsigned short*)(ws + 32 * MB);  // 8 MB
    float*          x2    = (float*)(ws + 40 * MB);           // 16 MB
    unsigned short* h2    = (unsigned short*)(ws + 56 * MB);  // 8 MB
    unsigned short* WqkT  = (unsigned short*)(ws + 64 * MB);  // 4 MB [2048][1024]
    unsigned short* WvT   = (unsigned short*)(ws + 68 * MB);  // 2 MB
    unsigned short* WoT   = (unsigned short*)(ws + 70 * MB);  // 2 MB
    unsigned short* W1T   = (unsigned short*)(ws + 72 * MB);  // 8 MB
    unsigned short* W2T   = (unsigned short*)(ws + 80 * MB);  // 8 MB  (total 88 MB)

    dim3 blk(256);
    wtrans_kernel<<<dim3(16, 16), blk, 0, stream>>>(Wq, WqkT, DM, DM, 0.125f);
    wtrans_kernel<<<dim3(16, 16), blk, 0, stream>>>(Wk, WqkT + DM * DM, DM, DM, 1.0f);
    wtrans_kernel<<<dim3(16, 16), blk, 0, stream>>>(Wv, WvT, DM, DM, 1.0f);
    wtrans_kernel<<<dim3(16, 16), blk, 0, stream>>>(Wo, WoT, DM, DM, 1.0f);
    wtrans_kernel<<<dim3(16, 64), blk, 0, stream>>>(W1, W1T, DM, DFF, 1.0f);
    wtrans_kernel<<<dim3(64, 16), blk, 0, stream>>>(W2, W2T, DFF, DM, 1.0f);

    ln_kernel<<<dim3(MT), blk, 0, stream>>>(x, ln1g, ln1b, xn1);

    // fused Q|K projection (N=2048) and transposed V projection
    gemm_pipe<0, 128, 256, 2, 4><<<dim3(32, 8), dim3(512), 0, stream>>>(
        xn1, WqkT, QKb, nullptr, nullptr, 2048, DM, 1.0f);
    gemm_pipe<4, 128, 128, 2, 2><<<dim3(32, 8), dim3(256), 0, stream>>>(
        xn1, WvT, VTg, nullptr, nullptr, DM, DM, 1.0f);

    attn_kernel<<<dim3(8, 32), dim3(512), 0, stream>>>(QKb, VTg, attno);

    gemm_pipe<1, 128, 128, 2, 2><<<dim3(32, 8), dim3(256), 0, stream>>>(
        attno, WoT, x2, nullptr, x, DM, DM, 1.0f);

    ln_kernel<<<dim3(MT), blk, 0, stream>>>(x2, ln2g, ln2b, h2);

    gemm_pipe<2, 256, 256, 2, 4><<<dim3(16, 16), dim3(512), 0, stream>>>(
        h2, W1T, ffa, b1, nullptr, DFF, DM, 1.0f);
    gemm_pipe<3, 128, 128, 2, 2><<<dim3(32, 8), dim3(256), 0, stream>>>(
        ffa, W2T, out, b2, x2, DM, DFF, 1.0f);
}